// Round 1
// baseline (909.046 us; speedup 1.0000x reference)
//
#include <hip/hip_runtime.h>
#include <math.h>

// ---------------------------------------------------------------------------
// GAT 3-layer forward. fp32 everywhere (round 0: correctness + sane perf).
// Pipeline per call:
//   1. Build CSR over dst (deg histogram -> block scan -> chunk scan -> scatter)
//   2. Per layer: GEMM (feat = h @ W), el/er reduction, per-node softmax+agg.
// ---------------------------------------------------------------------------

#define NEG_SLOPE 0.2f

// ---------------- CSR build ----------------

__global__ __launch_bounds__(256) void count_deg(const int* __restrict__ dst,
                                                 int* __restrict__ deg, int E) {
    int e = blockIdx.x * 256 + threadIdx.x;
    if (e < E) atomicAdd(&deg[dst[e]], 1);
}

// In-place exclusive scan of off[0..N) per 2048-elem chunk; chunk totals out.
__global__ __launch_bounds__(256) void scan_chunk(int* __restrict__ off,
                                                  int* __restrict__ chunkSum, int N) {
    __shared__ int sdata[256];
    int tid = threadIdx.x;
    int base = blockIdx.x * 2048 + tid * 8;
    int v[8];
    int tsum = 0;
#pragma unroll
    for (int j = 0; j < 8; ++j) {
        int idx = base + j;
        v[j] = (idx < N) ? off[idx] : 0;
        tsum += v[j];
    }
    sdata[tid] = tsum;
    __syncthreads();
    for (int o = 1; o < 256; o <<= 1) {
        int t = (tid >= o) ? sdata[tid - o] : 0;
        __syncthreads();
        sdata[tid] += t;
        __syncthreads();
    }
    int run = sdata[tid] - tsum;  // exclusive prefix for this thread's 8
#pragma unroll
    for (int j = 0; j < 8; ++j) {
        int idx = base + j;
        if (idx < N) off[idx] = run;
        run += v[j];
    }
    if (tid == 255) chunkSum[blockIdx.x] = sdata[255];
}

__global__ void scan_tail(const int* __restrict__ chunkSum, int* __restrict__ chunkOff,
                          int nchunks, int* __restrict__ off, int N, int E) {
    if (threadIdx.x == 0 && blockIdx.x == 0) {
        int run = 0;
        for (int c = 0; c < nchunks; ++c) { chunkOff[c] = run; run += chunkSum[c]; }
        off[N] = E;
    }
}

__global__ __launch_bounds__(256) void add_chunk_off(int* __restrict__ off,
                                                     int* __restrict__ cursor,
                                                     const int* __restrict__ chunkOff, int N) {
    int i = blockIdx.x * 256 + threadIdx.x;
    if (i < N) {
        int v = off[i] + chunkOff[i >> 11];
        off[i] = v;
        cursor[i] = v;
    }
}

__global__ __launch_bounds__(256) void scatter_edges(const int* __restrict__ src,
                                                     const int* __restrict__ dst,
                                                     int* __restrict__ cursor,
                                                     int* __restrict__ csr, int E) {
    int e = blockIdx.x * 256 + threadIdx.x;
    if (e < E) {
        int d = dst[e];
        int pos = atomicAdd(&cursor[d], 1);
        csr[pos] = src[e];
    }
}

// ---------------- GEMM: C[N,K] = A[N,F] @ W[F,K], fp32 ----------------
// 64x64 tile, 256 threads, 4x4 microtile, BK=16.

__global__ __launch_bounds__(256) void gemm_kernel(const float* __restrict__ A,
                                                   const float* __restrict__ W,
                                                   float* __restrict__ C,
                                                   int N, int F, int K) {
    __shared__ __align__(16) float As[16][68];  // +4 pad keeps float4 alignment, kills store conflicts
    __shared__ __align__(16) float Ws[16][64];
    int tid = threadIdx.x;
    int tx = tid & 15, ty = tid >> 4;
    int r0 = blockIdx.y * 64, c0 = blockIdx.x * 64;
    int arow = tid >> 2, akq = tid & 3;   // A tile load role: 64 rows x 4 quads
    int wk = tid >> 4, wcq = tid & 15;    // W tile load role: 16 k x 16 col-quads
    float acc[4][4] = {};

    for (int k0 = 0; k0 < F; k0 += 16) {
        float4 av = make_float4(0.f, 0.f, 0.f, 0.f);
        int gr = r0 + arow;
        if (gr < N) av = *(const float4*)&A[(size_t)gr * F + k0 + akq * 4];
        float4 wv = make_float4(0.f, 0.f, 0.f, 0.f);
        int gc = c0 + wcq * 4;
        if (gc < K) wv = *(const float4*)&W[(size_t)(k0 + wk) * K + gc];
        __syncthreads();
        As[akq * 4 + 0][arow] = av.x;
        As[akq * 4 + 1][arow] = av.y;
        As[akq * 4 + 2][arow] = av.z;
        As[akq * 4 + 3][arow] = av.w;
        *(float4*)&Ws[wk][wcq * 4] = wv;
        __syncthreads();
#pragma unroll
        for (int k = 0; k < 16; ++k) {
            float4 a = *(const float4*)&As[k][ty * 4];
            float4 w = *(const float4*)&Ws[k][tx * 4];
            acc[0][0] += a.x * w.x; acc[0][1] += a.x * w.y; acc[0][2] += a.x * w.z; acc[0][3] += a.x * w.w;
            acc[1][0] += a.y * w.x; acc[1][1] += a.y * w.y; acc[1][2] += a.y * w.z; acc[1][3] += a.y * w.w;
            acc[2][0] += a.z * w.x; acc[2][1] += a.z * w.y; acc[2][2] += a.z * w.z; acc[2][3] += a.z * w.w;
            acc[3][0] += a.w * w.x; acc[3][1] += a.w * w.y; acc[3][2] += a.w * w.z; acc[3][3] += a.w * w.w;
        }
    }
#pragma unroll
    for (int i = 0; i < 4; ++i) {
        int gr = r0 + ty * 4 + i;
        if (gr < N && (c0 + tx * 4) < K) {
            float4 o4 = make_float4(acc[i][0], acc[i][1], acc[i][2], acc[i][3]);
            *(float4*)&C[(size_t)gr * K + c0 + tx * 4] = o4;
        }
    }
}

// ---------------- el/er: el[n,h] = sum_d feat[n,h,d]*al[h,d] ----------------

template <int H, int D>
__global__ __launch_bounds__(256) void elr_kernel(const float* __restrict__ feat,
                                                  const float* __restrict__ al,
                                                  const float* __restrict__ ar,
                                                  float* __restrict__ el,
                                                  float* __restrict__ er, int N) {
    constexpr int HD = H * D;
    constexpr int G = 256 / HD;  // nodes per block
    int tid = threadIdx.x;
    int g = tid / HD;
    int rem = tid % HD;
    int h = rem / D;
    int d = rem % D;
    int n = blockIdx.x * G + g;
    float vl = 0.f, vr = 0.f;
    if (n < N) {
        float f = feat[(size_t)n * HD + rem];
        vl = f * al[rem];
        vr = f * ar[rem];
    }
#pragma unroll
    for (int o = D / 2; o >= 1; o >>= 1) {
        vl += __shfl_xor(vl, o);
        vr += __shfl_xor(vr, o);
    }
    if (n < N && d == 0) {
        el[n * H + h] = vl;
        er[n * H + h] = vr;
    }
}

// ---------------- per-node softmax + aggregation ----------------
// Block = H waves; wave h handles head h; lane = d for the aggregation.

template <int H, int D>
__global__ __launch_bounds__(H * 64) void agg_kernel(const float* __restrict__ feat,
                                                     const float* __restrict__ el,
                                                     const float* __restrict__ er,
                                                     const float* __restrict__ bias,
                                                     const int* __restrict__ off,
                                                     const int* __restrict__ csr,
                                                     float* __restrict__ out, int N) {
    int n = blockIdx.x;
    int h = threadIdx.x >> 6;
    int lane = threadIdx.x & 63;
    int begin = off[n], end = off[n + 1];
    float er_nh = er[n * H + h];

    // pass 1a: max
    float m = -INFINITY;
    for (int i = begin + lane; i < end; i += 64) {
        int s = csr[i];
        float e = el[s * H + h] + er_nh;
        e = e > 0.f ? e : NEG_SLOPE * e;
        m = fmaxf(m, e);
    }
#pragma unroll
    for (int o = 32; o >= 1; o >>= 1) m = fmaxf(m, __shfl_xor(m, o));

    // pass 1b: denom
    float ss = 0.f;
    for (int i = begin + lane; i < end; i += 64) {
        int s = csr[i];
        float e = el[s * H + h] + er_nh;
        e = e > 0.f ? e : NEG_SLOPE * e;
        ss += __expf(e - m);
    }
#pragma unroll
    for (int o = 32; o >= 1; o >>= 1) ss += __shfl_xor(ss, o);
    float inv = (end > begin) ? 1.f / ss : 0.f;

    // pass 2: aggregate (lane = d), edges serial
    float acc = 0.f;
    for (int i = begin; i < end; ++i) {
        int s = csr[i];
        float e = el[s * H + h] + er_nh;  // broadcast load, all lanes same addr
        e = e > 0.f ? e : NEG_SLOPE * e;
        float a = __expf(e - m) * inv;
        if (lane < D) acc += a * feat[(size_t)s * (H * D) + h * D + lane];
    }
    if (lane < D) out[(size_t)n * (H * D) + h * D + lane] = acc + bias[h * D + lane];
}

// ---------------- launch ----------------

extern "C" void kernel_launch(void* const* d_in, const int* in_sizes, int n_in,
                              void* d_out, int out_size, void* d_ws, size_t ws_size,
                              hipStream_t stream) {
    const float* inputs = (const float*)d_in[0];
    const float* W0 = (const float*)d_in[1];
    const float* al0 = (const float*)d_in[2];
    const float* ar0 = (const float*)d_in[3];
    const float* b0 = (const float*)d_in[4];
    const float* W1 = (const float*)d_in[5];
    const float* al1 = (const float*)d_in[6];
    const float* ar1 = (const float*)d_in[7];
    const float* b1 = (const float*)d_in[8];
    const float* W2 = (const float*)d_in[9];
    const float* al2 = (const float*)d_in[10];
    const float* ar2 = (const float*)d_in[11];
    const float* b2 = (const float*)d_in[12];
    const int* src = (const int*)d_in[13];
    const int* dst = (const int*)d_in[14];

    const int IN_DIM = 128;
    const int N = in_sizes[0] / IN_DIM;  // 50000
    const int E = in_sizes[13];          // 800000
    float* out = (float*)d_out;

    // workspace carve (256B aligned)
    char* base = (char*)d_ws;
    size_t o = 0;
    auto carve = [&](size_t bytes) -> void* {
        void* p = base + o;
        o += (bytes + 255) & ~(size_t)255;
        return p;
    };
    int* off = (int*)carve((size_t)(N + 1) * sizeof(int));
    int* cursor = (int*)carve((size_t)N * sizeof(int));
    int* chunkSum = (int*)carve(64 * sizeof(int));
    int* chunkOff = (int*)carve(64 * sizeof(int));
    int* csr = (int*)carve((size_t)E * sizeof(int));
    float* el = (float*)carve((size_t)N * 4 * sizeof(float));
    float* er = (float*)carve((size_t)N * 4 * sizeof(float));
    float* feat = (float*)carve((size_t)N * 256 * sizeof(float));
    float* hbuf = (float*)carve((size_t)N * 256 * sizeof(float));

    // ---- CSR build ----
    hipMemsetAsync(off, 0, (size_t)(N + 1) * sizeof(int), stream);
    int egrid = (E + 255) / 256;
    count_deg<<<egrid, 256, 0, stream>>>(dst, off, E);
    int nchunks = (N + 2047) / 2048;
    scan_chunk<<<nchunks, 256, 0, stream>>>(off, chunkSum, N);
    scan_tail<<<1, 64, 0, stream>>>(chunkSum, chunkOff, nchunks, off, N, E);
    add_chunk_off<<<(N + 255) / 256, 256, 0, stream>>>(off, cursor, chunkOff, N);
    scatter_edges<<<egrid, 256, 0, stream>>>(src, dst, cursor, csr, E);

    // ---- Layer 0: 128 -> 4x64 ----
    {
        dim3 grid((256 + 63) / 64, (N + 63) / 64);
        gemm_kernel<<<grid, 256, 0, stream>>>(inputs, W0, feat, N, 128, 256);
        elr_kernel<4, 64><<<N, 256, 0, stream>>>(feat, al0, ar0, el, er, N);
        agg_kernel<4, 64><<<N, 256, 0, stream>>>(feat, el, er, b0, off, csr, hbuf, N);
    }
    // ---- Layer 1: 256 -> 4x64 ----
    {
        dim3 grid((256 + 63) / 64, (N + 63) / 64);
        gemm_kernel<<<grid, 256, 0, stream>>>(hbuf, W1, feat, N, 256, 256);
        elr_kernel<4, 64><<<N, 256, 0, stream>>>(feat, al1, ar1, el, er, N);
        agg_kernel<4, 64><<<N, 256, 0, stream>>>(feat, el, er, b1, off, csr, hbuf, N);
    }
    // ---- Layer 2: 256 -> 1x16 (mean over 1 head == identity) ----
    {
        dim3 grid((16 + 63) / 64, (N + 63) / 64);
        gemm_kernel<<<grid, 256, 0, stream>>>(hbuf, W2, feat, N, 256, 16);
        elr_kernel<1, 16><<<(N + 15) / 16, 256, 0, stream>>>(feat, al2, ar2, el, er, N);
        agg_kernel<1, 16><<<N, 64, 0, stream>>>(feat, el, er, b2, off, csr, out, N);
    }
}

// Round 2
// 716.669 us; speedup vs baseline: 1.2684x; 1.2684x over previous
//
#include <hip/hip_runtime.h>
#include <math.h>

// ---------------------------------------------------------------------------
// GAT 3-layer forward. fp32.
// R2 change: agg_kernel restructured for memory-level parallelism:
//   - alpha + src cached in LDS (computed once, not 3x)
//   - aggregation loop unrolled x8 (8 independent feat-row gathers in flight)
//   - D=16 layer packs 4 edge-slots per wave (all 64 lanes active)
// ---------------------------------------------------------------------------

#define NEG_SLOPE 0.2f

// ---------------- CSR build ----------------

__global__ __launch_bounds__(256) void count_deg(const int* __restrict__ dst,
                                                 int* __restrict__ deg, int E) {
    int e = blockIdx.x * 256 + threadIdx.x;
    if (e < E) atomicAdd(&deg[dst[e]], 1);
}

__global__ __launch_bounds__(256) void scan_chunk(int* __restrict__ off,
                                                  int* __restrict__ chunkSum, int N) {
    __shared__ int sdata[256];
    int tid = threadIdx.x;
    int base = blockIdx.x * 2048 + tid * 8;
    int v[8];
    int tsum = 0;
#pragma unroll
    for (int j = 0; j < 8; ++j) {
        int idx = base + j;
        v[j] = (idx < N) ? off[idx] : 0;
        tsum += v[j];
    }
    sdata[tid] = tsum;
    __syncthreads();
    for (int o = 1; o < 256; o <<= 1) {
        int t = (tid >= o) ? sdata[tid - o] : 0;
        __syncthreads();
        sdata[tid] += t;
        __syncthreads();
    }
    int run = sdata[tid] - tsum;
#pragma unroll
    for (int j = 0; j < 8; ++j) {
        int idx = base + j;
        if (idx < N) off[idx] = run;
        run += v[j];
    }
    if (tid == 255) chunkSum[blockIdx.x] = sdata[255];
}

__global__ void scan_tail(const int* __restrict__ chunkSum, int* __restrict__ chunkOff,
                          int nchunks, int* __restrict__ off, int N, int E) {
    if (threadIdx.x == 0 && blockIdx.x == 0) {
        int run = 0;
        for (int c = 0; c < nchunks; ++c) { chunkOff[c] = run; run += chunkSum[c]; }
        off[N] = E;
    }
}

__global__ __launch_bounds__(256) void add_chunk_off(int* __restrict__ off,
                                                     int* __restrict__ cursor,
                                                     const int* __restrict__ chunkOff, int N) {
    int i = blockIdx.x * 256 + threadIdx.x;
    if (i < N) {
        int v = off[i] + chunkOff[i >> 11];
        off[i] = v;
        cursor[i] = v;
    }
}

__global__ __launch_bounds__(256) void scatter_edges(const int* __restrict__ src,
                                                     const int* __restrict__ dst,
                                                     int* __restrict__ cursor,
                                                     int* __restrict__ csr, int E) {
    int e = blockIdx.x * 256 + threadIdx.x;
    if (e < E) {
        int d = dst[e];
        int pos = atomicAdd(&cursor[d], 1);
        csr[pos] = src[e];
    }
}

// ---------------- GEMM: C[N,K] = A[N,F] @ W[F,K], fp32 ----------------

__global__ __launch_bounds__(256) void gemm_kernel(const float* __restrict__ A,
                                                   const float* __restrict__ W,
                                                   float* __restrict__ C,
                                                   int N, int F, int K) {
    __shared__ __align__(16) float As[16][68];
    __shared__ __align__(16) float Ws[16][64];
    int tid = threadIdx.x;
    int tx = tid & 15, ty = tid >> 4;
    int r0 = blockIdx.y * 64, c0 = blockIdx.x * 64;
    int arow = tid >> 2, akq = tid & 3;
    int wk = tid >> 4, wcq = tid & 15;
    float acc[4][4] = {};

    for (int k0 = 0; k0 < F; k0 += 16) {
        float4 av = make_float4(0.f, 0.f, 0.f, 0.f);
        int gr = r0 + arow;
        if (gr < N) av = *(const float4*)&A[(size_t)gr * F + k0 + akq * 4];
        float4 wv = make_float4(0.f, 0.f, 0.f, 0.f);
        int gc = c0 + wcq * 4;
        if (gc < K) wv = *(const float4*)&W[(size_t)(k0 + wk) * K + gc];
        __syncthreads();
        As[akq * 4 + 0][arow] = av.x;
        As[akq * 4 + 1][arow] = av.y;
        As[akq * 4 + 2][arow] = av.z;
        As[akq * 4 + 3][arow] = av.w;
        *(float4*)&Ws[wk][wcq * 4] = wv;
        __syncthreads();
#pragma unroll
        for (int k = 0; k < 16; ++k) {
            float4 a = *(const float4*)&As[k][ty * 4];
            float4 w = *(const float4*)&Ws[k][tx * 4];
            acc[0][0] += a.x * w.x; acc[0][1] += a.x * w.y; acc[0][2] += a.x * w.z; acc[0][3] += a.x * w.w;
            acc[1][0] += a.y * w.x; acc[1][1] += a.y * w.y; acc[1][2] += a.y * w.z; acc[1][3] += a.y * w.w;
            acc[2][0] += a.z * w.x; acc[2][1] += a.z * w.y; acc[2][2] += a.z * w.z; acc[2][3] += a.z * w.w;
            acc[3][0] += a.w * w.x; acc[3][1] += a.w * w.y; acc[3][2] += a.w * w.z; acc[3][3] += a.w * w.w;
        }
    }
#pragma unroll
    for (int i = 0; i < 4; ++i) {
        int gr = r0 + ty * 4 + i;
        if (gr < N && (c0 + tx * 4) < K) {
            float4 o4 = make_float4(acc[i][0], acc[i][1], acc[i][2], acc[i][3]);
            *(float4*)&C[(size_t)gr * K + c0 + tx * 4] = o4;
        }
    }
}

// ---------------- el/er ----------------

template <int H, int D>
__global__ __launch_bounds__(256) void elr_kernel(const float* __restrict__ feat,
                                                  const float* __restrict__ al,
                                                  const float* __restrict__ ar,
                                                  float* __restrict__ el,
                                                  float* __restrict__ er, int N) {
    constexpr int HD = H * D;
    constexpr int G = 256 / HD;
    int tid = threadIdx.x;
    int g = tid / HD;
    int rem = tid % HD;
    int h = rem / D;
    int d = rem % D;
    int n = blockIdx.x * G + g;
    float vl = 0.f, vr = 0.f;
    if (n < N) {
        float f = feat[(size_t)n * HD + rem];
        vl = f * al[rem];
        vr = f * ar[rem];
    }
#pragma unroll
    for (int o = D / 2; o >= 1; o >>= 1) {
        vl += __shfl_xor(vl, o);
        vr += __shfl_xor(vr, o);
    }
    if (n < N && d == 0) {
        el[n * H + h] = vl;
        er[n * H + h] = vr;
    }
}

// ---------------- per-node softmax + aggregation (v2: MLP-oriented) --------
// Block = H waves; wave h = head h.
// Phase 1: gather el once, e -> LDS, wave max.
// Phase 2: exp(e-m) -> LDS (unnormalized alpha), wave sum.
// Phase 3: unrolled-by-U aggregation, U independent feat row gathers in
//          flight; ES = 64/D edge slots per wave so all lanes work for D<64.
// deg > CAP spill path kept for correctness (never hit: max deg ~45).

template <int H, int D, int CAP, int U>
__global__ __launch_bounds__(H * 64) void agg_kernel(const float* __restrict__ feat,
                                                     const float* __restrict__ el,
                                                     const float* __restrict__ er,
                                                     const float* __restrict__ bias,
                                                     const int* __restrict__ off,
                                                     const int* __restrict__ csr,
                                                     float* __restrict__ out, int N) {
    constexpr int HD = H * D;
    constexpr int ES = 64 / D;  // edge slots per wave in phase 3
    __shared__ float s_alpha[H][CAP];
    __shared__ int s_src[CAP];
    int n = blockIdx.x;
    int h = threadIdx.x >> 6;
    int lane = threadIdx.x & 63;
    int begin = off[n];
    int deg = off[n + 1] - begin;
    float er_nh = er[n * H + h];

    // Phase 1: e values + max
    float m = -INFINITY;
    for (int i = lane; i < deg; i += 64) {
        int s = csr[begin + i];
        if (h == 0 && i < CAP) s_src[i] = s;
        float e = el[s * H + h] + er_nh;
        e = e > 0.f ? e : NEG_SLOPE * e;
        if (i < CAP) s_alpha[h][i] = e;
        m = fmaxf(m, e);
    }
#pragma unroll
    for (int o = 32; o >= 1; o >>= 1) m = fmaxf(m, __shfl_xor(m, o));

    // Phase 2: exp + sum (same lane re-reads its own LDS writes)
    float ss = 0.f;
    for (int i = lane; i < deg; i += 64) {
        float e;
        if (i < CAP) e = s_alpha[h][i];
        else {
            int s = csr[begin + i];
            e = el[s * H + h] + er_nh;
            e = e > 0.f ? e : NEG_SLOPE * e;
        }
        float x = __expf(e - m);
        ss += x;
        if (i < CAP) s_alpha[h][i] = x;
    }
#pragma unroll
    for (int o = 32; o >= 1; o >>= 1) ss += __shfl_xor(ss, o);
    float inv = (deg > 0) ? 1.f / ss : 0.f;

    __syncthreads();  // s_src (wave 0) visible to all waves

    // Phase 3: aggregate. slot-packed lanes, unroll U.
    int slot = lane / D;
    int d = lane % D;
    int dcap = deg < CAP ? deg : CAP;
    float acc = 0.f;
    int j = slot;
    for (; j + (U - 1) * ES < dcap; j += U * ES) {
        float a[U], f[U];
        int s[U];
#pragma unroll
        for (int u = 0; u < U; ++u) {
            int idx = j + u * ES;
            s[u] = s_src[idx];
            a[u] = s_alpha[h][idx];
        }
#pragma unroll
        for (int u = 0; u < U; ++u)
            f[u] = feat[(size_t)s[u] * HD + h * D + d];
#pragma unroll
        for (int u = 0; u < U; ++u) acc += a[u] * f[u];
    }
    for (; j < dcap; j += ES) {
        float a = s_alpha[h][j];
        int s = s_src[j];
        acc += a * feat[(size_t)s * HD + h * D + d];
    }
    // spill path (deg > CAP) — correctness only
    for (int i = CAP + slot; i < deg; i += ES) {
        int s = csr[begin + i];
        float e = el[s * H + h] + er_nh;
        e = e > 0.f ? e : NEG_SLOPE * e;
        acc += __expf(e - m) * feat[(size_t)s * HD + h * D + d];
    }
#pragma unroll
    for (int o = D; o < 64; o <<= 1) acc += __shfl_xor(acc, o);
    if (lane < D)
        out[(size_t)n * HD + h * D + d] = acc * inv + bias[h * D + d];
}

// ---------------- launch ----------------

extern "C" void kernel_launch(void* const* d_in, const int* in_sizes, int n_in,
                              void* d_out, int out_size, void* d_ws, size_t ws_size,
                              hipStream_t stream) {
    const float* inputs = (const float*)d_in[0];
    const float* W0 = (const float*)d_in[1];
    const float* al0 = (const float*)d_in[2];
    const float* ar0 = (const float*)d_in[3];
    const float* b0 = (const float*)d_in[4];
    const float* W1 = (const float*)d_in[5];
    const float* al1 = (const float*)d_in[6];
    const float* ar1 = (const float*)d_in[7];
    const float* b1 = (const float*)d_in[8];
    const float* W2 = (const float*)d_in[9];
    const float* al2 = (const float*)d_in[10];
    const float* ar2 = (const float*)d_in[11];
    const float* b2 = (const float*)d_in[12];
    const int* src = (const int*)d_in[13];
    const int* dst = (const int*)d_in[14];

    const int IN_DIM = 128;
    const int N = in_sizes[0] / IN_DIM;  // 50000
    const int E = in_sizes[13];          // 800000
    float* out = (float*)d_out;

    char* base = (char*)d_ws;
    size_t o = 0;
    auto carve = [&](size_t bytes) -> void* {
        void* p = base + o;
        o += (bytes + 255) & ~(size_t)255;
        return p;
    };
    int* off = (int*)carve((size_t)(N + 1) * sizeof(int));
    int* cursor = (int*)carve((size_t)N * sizeof(int));
    int* chunkSum = (int*)carve(64 * sizeof(int));
    int* chunkOff = (int*)carve(64 * sizeof(int));
    int* csr = (int*)carve((size_t)E * sizeof(int));
    float* el = (float*)carve((size_t)N * 4 * sizeof(float));
    float* er = (float*)carve((size_t)N * 4 * sizeof(float));
    float* feat = (float*)carve((size_t)N * 256 * sizeof(float));
    float* hbuf = (float*)carve((size_t)N * 256 * sizeof(float));

    // ---- CSR build ----
    hipMemsetAsync(off, 0, (size_t)(N + 1) * sizeof(int), stream);
    int egrid = (E + 255) / 256;
    count_deg<<<egrid, 256, 0, stream>>>(dst, off, E);
    int nchunks = (N + 2047) / 2048;
    scan_chunk<<<nchunks, 256, 0, stream>>>(off, chunkSum, N);
    scan_tail<<<1, 64, 0, stream>>>(chunkSum, chunkOff, nchunks, off, N, E);
    add_chunk_off<<<(N + 255) / 256, 256, 0, stream>>>(off, cursor, chunkOff, N);
    scatter_edges<<<egrid, 256, 0, stream>>>(src, dst, cursor, csr, E);

    // ---- Layer 0: 128 -> 4x64 ----
    {
        dim3 grid((256 + 63) / 64, (N + 63) / 64);
        gemm_kernel<<<grid, 256, 0, stream>>>(inputs, W0, feat, N, 128, 256);
        elr_kernel<4, 64><<<N, 256, 0, stream>>>(feat, al0, ar0, el, er, N);
        agg_kernel<4, 64, 512, 8><<<N, 256, 0, stream>>>(feat, el, er, b0, off, csr, hbuf, N);
    }
    // ---- Layer 1: 256 -> 4x64 ----
    {
        dim3 grid((256 + 63) / 64, (N + 63) / 64);
        gemm_kernel<<<grid, 256, 0, stream>>>(hbuf, W1, feat, N, 256, 256);
        elr_kernel<4, 64><<<N, 256, 0, stream>>>(feat, al1, ar1, el, er, N);
        agg_kernel<4, 64, 512, 8><<<N, 256, 0, stream>>>(feat, el, er, b1, off, csr, hbuf, N);
    }
    // ---- Layer 2: 256 -> 1x16 ----
    {
        dim3 grid((16 + 63) / 64, (N + 63) / 64);
        gemm_kernel<<<grid, 256, 0, stream>>>(hbuf, W2, feat, N, 256, 16);
        elr_kernel<1, 16><<<(N + 15) / 16, 256, 0, stream>>>(feat, al2, ar2, el, er, N);
        agg_kernel<1, 16, 512, 4><<<N, 64, 0, stream>>>(feat, el, er, b2, off, csr, out, N);
    }
}

// Round 3
// 657.164 us; speedup vs baseline: 1.3833x; 1.0905x over previous
//
#include <hip/hip_runtime.h>
#include <hip/hip_bf16.h>
#include <math.h>

// ---------------------------------------------------------------------------
// GAT 3-layer forward.
// R3 change: agg gathers feat in bf16 (written as a side-product of elr),
// alpha/softmax/accumulate stay fp32. bf16x2 packed loads -> D/2 lanes per
// edge slot -> 2x edge slots in flight (D=64: ES=2, D=16: ES=8).
// ---------------------------------------------------------------------------

#define NEG_SLOPE 0.2f

// ---------------- CSR build ----------------

__global__ __launch_bounds__(256) void count_deg(const int* __restrict__ dst,
                                                 int* __restrict__ deg, int E) {
    int e = blockIdx.x * 256 + threadIdx.x;
    if (e < E) atomicAdd(&deg[dst[e]], 1);
}

__global__ __launch_bounds__(256) void scan_chunk(int* __restrict__ off,
                                                  int* __restrict__ chunkSum, int N) {
    __shared__ int sdata[256];
    int tid = threadIdx.x;
    int base = blockIdx.x * 2048 + tid * 8;
    int v[8];
    int tsum = 0;
#pragma unroll
    for (int j = 0; j < 8; ++j) {
        int idx = base + j;
        v[j] = (idx < N) ? off[idx] : 0;
        tsum += v[j];
    }
    sdata[tid] = tsum;
    __syncthreads();
    for (int o = 1; o < 256; o <<= 1) {
        int t = (tid >= o) ? sdata[tid - o] : 0;
        __syncthreads();
        sdata[tid] += t;
        __syncthreads();
    }
    int run = sdata[tid] - tsum;
#pragma unroll
    for (int j = 0; j < 8; ++j) {
        int idx = base + j;
        if (idx < N) off[idx] = run;
        run += v[j];
    }
    if (tid == 255) chunkSum[blockIdx.x] = sdata[255];
}

__global__ void scan_tail(const int* __restrict__ chunkSum, int* __restrict__ chunkOff,
                          int nchunks, int* __restrict__ off, int N, int E) {
    if (threadIdx.x == 0 && blockIdx.x == 0) {
        int run = 0;
        for (int c = 0; c < nchunks; ++c) { chunkOff[c] = run; run += chunkSum[c]; }
        off[N] = E;
    }
}

__global__ __launch_bounds__(256) void add_chunk_off(int* __restrict__ off,
                                                     int* __restrict__ cursor,
                                                     const int* __restrict__ chunkOff, int N) {
    int i = blockIdx.x * 256 + threadIdx.x;
    if (i < N) {
        int v = off[i] + chunkOff[i >> 11];
        off[i] = v;
        cursor[i] = v;
    }
}

__global__ __launch_bounds__(256) void scatter_edges(const int* __restrict__ src,
                                                     const int* __restrict__ dst,
                                                     int* __restrict__ cursor,
                                                     int* __restrict__ csr, int E) {
    int e = blockIdx.x * 256 + threadIdx.x;
    if (e < E) {
        int d = dst[e];
        int pos = atomicAdd(&cursor[d], 1);
        csr[pos] = src[e];
    }
}

// ---------------- GEMM: C[N,K] = A[N,F] @ W[F,K], fp32 ----------------

__global__ __launch_bounds__(256) void gemm_kernel(const float* __restrict__ A,
                                                   const float* __restrict__ W,
                                                   float* __restrict__ C,
                                                   int N, int F, int K) {
    __shared__ __align__(16) float As[16][68];
    __shared__ __align__(16) float Ws[16][64];
    int tid = threadIdx.x;
    int tx = tid & 15, ty = tid >> 4;
    int r0 = blockIdx.y * 64, c0 = blockIdx.x * 64;
    int arow = tid >> 2, akq = tid & 3;
    int wk = tid >> 4, wcq = tid & 15;
    float acc[4][4] = {};

    for (int k0 = 0; k0 < F; k0 += 16) {
        float4 av = make_float4(0.f, 0.f, 0.f, 0.f);
        int gr = r0 + arow;
        if (gr < N) av = *(const float4*)&A[(size_t)gr * F + k0 + akq * 4];
        float4 wv = make_float4(0.f, 0.f, 0.f, 0.f);
        int gc = c0 + wcq * 4;
        if (gc < K) wv = *(const float4*)&W[(size_t)(k0 + wk) * K + gc];
        __syncthreads();
        As[akq * 4 + 0][arow] = av.x;
        As[akq * 4 + 1][arow] = av.y;
        As[akq * 4 + 2][arow] = av.z;
        As[akq * 4 + 3][arow] = av.w;
        *(float4*)&Ws[wk][wcq * 4] = wv;
        __syncthreads();
#pragma unroll
        for (int k = 0; k < 16; ++k) {
            float4 a = *(const float4*)&As[k][ty * 4];
            float4 w = *(const float4*)&Ws[k][tx * 4];
            acc[0][0] += a.x * w.x; acc[0][1] += a.x * w.y; acc[0][2] += a.x * w.z; acc[0][3] += a.x * w.w;
            acc[1][0] += a.y * w.x; acc[1][1] += a.y * w.y; acc[1][2] += a.y * w.z; acc[1][3] += a.y * w.w;
            acc[2][0] += a.z * w.x; acc[2][1] += a.z * w.y; acc[2][2] += a.z * w.z; acc[2][3] += a.z * w.w;
            acc[3][0] += a.w * w.x; acc[3][1] += a.w * w.y; acc[3][2] += a.w * w.z; acc[3][3] += a.w * w.w;
        }
    }
#pragma unroll
    for (int i = 0; i < 4; ++i) {
        int gr = r0 + ty * 4 + i;
        if (gr < N && (c0 + tx * 4) < K) {
            float4 o4 = make_float4(acc[i][0], acc[i][1], acc[i][2], acc[i][3]);
            *(float4*)&C[(size_t)gr * K + c0 + tx * 4] = o4;
        }
    }
}

// ---------------- el/er + bf16 cast of feat ----------------

template <int H, int D>
__global__ __launch_bounds__(256) void elr_kernel(const float* __restrict__ feat,
                                                  const float* __restrict__ al,
                                                  const float* __restrict__ ar,
                                                  float* __restrict__ el,
                                                  float* __restrict__ er,
                                                  __hip_bfloat16* __restrict__ featb, int N) {
    constexpr int HD = H * D;
    constexpr int G = 256 / HD;
    int tid = threadIdx.x;
    int g = tid / HD;
    int rem = tid % HD;
    int h = rem / D;
    int d = rem % D;
    int n = blockIdx.x * G + g;
    float vl = 0.f, vr = 0.f;
    if (n < N) {
        float f = feat[(size_t)n * HD + rem];
        featb[(size_t)n * HD + rem] = __float2bfloat16(f);
        vl = f * al[rem];
        vr = f * ar[rem];
    }
#pragma unroll
    for (int o = D / 2; o >= 1; o >>= 1) {
        vl += __shfl_xor(vl, o);
        vr += __shfl_xor(vr, o);
    }
    if (n < N && d == 0) {
        el[n * H + h] = vl;
        er[n * H + h] = vr;
    }
}

// ---------------- per-node softmax + aggregation (v3: bf16 gather) --------
// Block = H waves; wave h = head h.
// Phase 1: gather el once, leaky-relu(e) -> LDS, wave max.
// Phase 2: exp(e-m) -> LDS (unnormalized alpha), wave sum.
// Phase 3: bf16x2 gather: L=D/2 lanes per edge slot, ES=64/L slots per wave,
//          unrolled by U -> U*ES independent feat-row gathers in flight.

template <int H, int D, int CAP, int U>
__global__ __launch_bounds__(H * 64) void agg_kernel(const __hip_bfloat16* __restrict__ featb,
                                                     const float* __restrict__ feat,
                                                     const float* __restrict__ el,
                                                     const float* __restrict__ er,
                                                     const float* __restrict__ bias,
                                                     const int* __restrict__ off,
                                                     const int* __restrict__ csr,
                                                     float* __restrict__ out, int N) {
    constexpr int HD = H * D;
    constexpr int L = D / 2;    // lanes per edge slot (bf16 pair per lane)
    constexpr int ES = 64 / L;  // edge slots per wave
    __shared__ float s_alpha[H][CAP];
    __shared__ int s_src[CAP];
    int n = blockIdx.x;
    int h = threadIdx.x >> 6;
    int lane = threadIdx.x & 63;
    int begin = off[n];
    int deg = off[n + 1] - begin;
    float er_nh = er[n * H + h];

    // Phase 1: e values + max
    float m = -INFINITY;
    for (int i = lane; i < deg; i += 64) {
        int s = csr[begin + i];
        if (h == 0 && i < CAP) s_src[i] = s;
        float e = el[s * H + h] + er_nh;
        e = e > 0.f ? e : NEG_SLOPE * e;
        if (i < CAP) s_alpha[h][i] = e;
        m = fmaxf(m, e);
    }
#pragma unroll
    for (int o = 32; o >= 1; o >>= 1) m = fmaxf(m, __shfl_xor(m, o));

    // Phase 2: exp + sum
    float ss = 0.f;
    for (int i = lane; i < deg; i += 64) {
        float e;
        if (i < CAP) e = s_alpha[h][i];
        else {
            int s = csr[begin + i];
            e = el[s * H + h] + er_nh;
            e = e > 0.f ? e : NEG_SLOPE * e;
        }
        float x = __expf(e - m);
        ss += x;
        if (i < CAP) s_alpha[h][i] = x;
    }
#pragma unroll
    for (int o = 32; o >= 1; o >>= 1) ss += __shfl_xor(ss, o);
    float inv = (deg > 0) ? 1.f / ss : 0.f;

    __syncthreads();  // s_src (wave 0) + s_alpha visible to all

    // Phase 3: aggregate over bf16 feat rows.
    int slot = lane / L;
    int p = lane % L;  // handles d = 2p, 2p+1
    int dcap = deg < CAP ? deg : CAP;
    const unsigned int* frow = (const unsigned int*)featb;
    size_t colOff = (size_t)(h * D) / 2 + p;
    float accx = 0.f, accy = 0.f;
    int j = slot;
    for (; j + (U - 1) * ES < dcap; j += U * ES) {
        float a[U];
        unsigned int f[U];
        int s[U];
#pragma unroll
        for (int u = 0; u < U; ++u) {
            int idx = j + u * ES;
            s[u] = s_src[idx];
            a[u] = s_alpha[h][idx];
        }
#pragma unroll
        for (int u = 0; u < U; ++u)
            f[u] = frow[(size_t)s[u] * (HD / 2) + colOff];
#pragma unroll
        for (int u = 0; u < U; ++u) {
            float lo = __uint_as_float(f[u] << 16);
            float hi = __uint_as_float(f[u] & 0xffff0000u);
            accx += a[u] * lo;
            accy += a[u] * hi;
        }
    }
    for (; j < dcap; j += ES) {
        float a = s_alpha[h][j];
        unsigned int f = frow[(size_t)s_src[j] * (HD / 2) + colOff];
        accx += a * __uint_as_float(f << 16);
        accy += a * __uint_as_float(f & 0xffff0000u);
    }
    // spill path (deg > CAP) — correctness only, fp32 feat
    for (int i = CAP + slot; i < deg; i += ES) {
        int s = csr[begin + i];
        float e = el[s * H + h] + er_nh;
        e = e > 0.f ? e : NEG_SLOPE * e;
        float w = __expf(e - m);
        accx += w * feat[(size_t)s * HD + h * D + 2 * p];
        accy += w * feat[(size_t)s * HD + h * D + 2 * p + 1];
    }
#pragma unroll
    for (int o = L; o < 64; o <<= 1) {
        accx += __shfl_xor(accx, o);
        accy += __shfl_xor(accy, o);
    }
    if (lane < L) {
        float2 o2 = make_float2(accx * inv + bias[h * D + 2 * p],
                                accy * inv + bias[h * D + 2 * p + 1]);
        *(float2*)&out[(size_t)n * HD + h * D + 2 * p] = o2;
    }
}

// ---------------- launch ----------------

extern "C" void kernel_launch(void* const* d_in, const int* in_sizes, int n_in,
                              void* d_out, int out_size, void* d_ws, size_t ws_size,
                              hipStream_t stream) {
    const float* inputs = (const float*)d_in[0];
    const float* W0 = (const float*)d_in[1];
    const float* al0 = (const float*)d_in[2];
    const float* ar0 = (const float*)d_in[3];
    const float* b0 = (const float*)d_in[4];
    const float* W1 = (const float*)d_in[5];
    const float* al1 = (const float*)d_in[6];
    const float* ar1 = (const float*)d_in[7];
    const float* b1 = (const float*)d_in[8];
    const float* W2 = (const float*)d_in[9];
    const float* al2 = (const float*)d_in[10];
    const float* ar2 = (const float*)d_in[11];
    const float* b2 = (const float*)d_in[12];
    const int* src = (const int*)d_in[13];
    const int* dst = (const int*)d_in[14];

    const int IN_DIM = 128;
    const int N = in_sizes[0] / IN_DIM;  // 50000
    const int E = in_sizes[13];          // 800000
    float* out = (float*)d_out;

    char* base = (char*)d_ws;
    size_t o = 0;
    auto carve = [&](size_t bytes) -> void* {
        void* p = base + o;
        o += (bytes + 255) & ~(size_t)255;
        return p;
    };
    int* off = (int*)carve((size_t)(N + 1) * sizeof(int));
    int* cursor = (int*)carve((size_t)N * sizeof(int));
    int* chunkSum = (int*)carve(64 * sizeof(int));
    int* chunkOff = (int*)carve(64 * sizeof(int));
    int* csr = (int*)carve((size_t)E * sizeof(int));
    float* el = (float*)carve((size_t)N * 4 * sizeof(float));
    float* er = (float*)carve((size_t)N * 4 * sizeof(float));
    float* feat = (float*)carve((size_t)N * 256 * sizeof(float));
    float* hbuf = (float*)carve((size_t)N * 256 * sizeof(float));
    __hip_bfloat16* featb = (__hip_bfloat16*)carve((size_t)N * 256 * sizeof(__hip_bfloat16));

    // ---- CSR build ----
    hipMemsetAsync(off, 0, (size_t)(N + 1) * sizeof(int), stream);
    int egrid = (E + 255) / 256;
    count_deg<<<egrid, 256, 0, stream>>>(dst, off, E);
    int nchunks = (N + 2047) / 2048;
    scan_chunk<<<nchunks, 256, 0, stream>>>(off, chunkSum, N);
    scan_tail<<<1, 64, 0, stream>>>(chunkSum, chunkOff, nchunks, off, N, E);
    add_chunk_off<<<(N + 255) / 256, 256, 0, stream>>>(off, cursor, chunkOff, N);
    scatter_edges<<<egrid, 256, 0, stream>>>(src, dst, cursor, csr, E);

    // ---- Layer 0: 128 -> 4x64 ----
    {
        dim3 grid((256 + 63) / 64, (N + 63) / 64);
        gemm_kernel<<<grid, 256, 0, stream>>>(inputs, W0, feat, N, 128, 256);
        elr_kernel<4, 64><<<N, 256, 0, stream>>>(feat, al0, ar0, el, er, featb, N);
        agg_kernel<4, 64, 512, 8><<<N, 256, 0, stream>>>(featb, feat, el, er, b0, off, csr, hbuf, N);
    }
    // ---- Layer 1: 256 -> 4x64 ----
    {
        dim3 grid((256 + 63) / 64, (N + 63) / 64);
        gemm_kernel<<<grid, 256, 0, stream>>>(hbuf, W1, feat, N, 256, 256);
        elr_kernel<4, 64><<<N, 256, 0, stream>>>(feat, al1, ar1, el, er, featb, N);
        agg_kernel<4, 64, 512, 8><<<N, 256, 0, stream>>>(featb, feat, el, er, b1, off, csr, hbuf, N);
    }
    // ---- Layer 2: 256 -> 1x16 ----
    {
        dim3 grid((16 + 63) / 64, (N + 63) / 64);
        gemm_kernel<<<grid, 256, 0, stream>>>(hbuf, W2, feat, N, 256, 16);
        elr_kernel<1, 16><<<(N + 15) / 16, 256, 0, stream>>>(feat, al2, ar2, el, er, featb, N);
        agg_kernel<1, 16, 512, 2><<<N, 64, 0, stream>>>(featb, feat, el, er, b2, off, csr, out, N);
    }
}

// Round 4
// 591.070 us; speedup vs baseline: 1.5380x; 1.1118x over previous
//
#include <hip/hip_runtime.h>
#include <hip/hip_bf16.h>
#include <math.h>

// ---------------------------------------------------------------------------
// GAT 3-layer forward.
// R4 change: layers 0/1 GEMM moved to MFMA with split-bf16 (3-term):
//   x = hi + lo (bf16 each);  A*W ~= Ahi*Whi + Ahi*Wlo + Alo*Whi
// giving ~fp32 accuracy at 3x MFMA work on the 2.5 PF matrix pipe.
// A is split in-kernel from fp32 (no big prep arrays); W is pre-split +
// transposed once per call (tiny). Layer-2 GEMM (K=16) stays fp32 vector.
// ---------------------------------------------------------------------------

#define NEG_SLOPE 0.2f

typedef __attribute__((ext_vector_type(8))) short v8s;   // 8 bf16 in 4 VGPRs
typedef __attribute__((ext_vector_type(4))) float f32x4;

// ---------------- CSR build ----------------

__global__ __launch_bounds__(256) void count_deg(const int* __restrict__ dst,
                                                 int* __restrict__ deg, int E) {
    int e = blockIdx.x * 256 + threadIdx.x;
    if (e < E) atomicAdd(&deg[dst[e]], 1);
}

__global__ __launch_bounds__(256) void scan_chunk(int* __restrict__ off,
                                                  int* __restrict__ chunkSum, int N) {
    __shared__ int sdata[256];
    int tid = threadIdx.x;
    int base = blockIdx.x * 2048 + tid * 8;
    int v[8];
    int tsum = 0;
#pragma unroll
    for (int j = 0; j < 8; ++j) {
        int idx = base + j;
        v[j] = (idx < N) ? off[idx] : 0;
        tsum += v[j];
    }
    sdata[tid] = tsum;
    __syncthreads();
    for (int o = 1; o < 256; o <<= 1) {
        int t = (tid >= o) ? sdata[tid - o] : 0;
        __syncthreads();
        sdata[tid] += t;
        __syncthreads();
    }
    int run = sdata[tid] - tsum;
#pragma unroll
    for (int j = 0; j < 8; ++j) {
        int idx = base + j;
        if (idx < N) off[idx] = run;
        run += v[j];
    }
    if (tid == 255) chunkSum[blockIdx.x] = sdata[255];
}

__global__ void scan_tail(const int* __restrict__ chunkSum, int* __restrict__ chunkOff,
                          int nchunks, int* __restrict__ off, int N, int E) {
    if (threadIdx.x == 0 && blockIdx.x == 0) {
        int run = 0;
        for (int c = 0; c < nchunks; ++c) { chunkOff[c] = run; run += chunkSum[c]; }
        off[N] = E;
    }
}

__global__ __launch_bounds__(256) void add_chunk_off(int* __restrict__ off,
                                                     int* __restrict__ cursor,
                                                     const int* __restrict__ chunkOff, int N) {
    int i = blockIdx.x * 256 + threadIdx.x;
    if (i < N) {
        int v = off[i] + chunkOff[i >> 11];
        off[i] = v;
        cursor[i] = v;
    }
}

__global__ __launch_bounds__(256) void scatter_edges(const int* __restrict__ src,
                                                     const int* __restrict__ dst,
                                                     int* __restrict__ cursor,
                                                     int* __restrict__ csr, int E) {
    int e = blockIdx.x * 256 + threadIdx.x;
    if (e < E) {
        int d = dst[e];
        int pos = atomicAdd(&cursor[d], 1);
        csr[pos] = src[e];
    }
}

// ---------------- bf16 split helpers ----------------

__device__ __forceinline__ unsigned short bf16_rne(float x) {
    unsigned int u = __float_as_uint(x);
    return (unsigned short)((u + 0x7fffu + ((u >> 16) & 1u)) >> 16);
}

// W prep: read W[F][K] fp32, write Wt_hi/Wt_lo as [K][F] bf16 (transposed).
__global__ __launch_bounds__(256) void wsplit(const float* __restrict__ W,
                                              unsigned short* __restrict__ thi,
                                              unsigned short* __restrict__ tlo,
                                              int F, int K) {
    int idx = blockIdx.x * 256 + threadIdx.x;
    if (idx >= F * K) return;
    int f = idx / K, k = idx % K;
    float v = W[idx];
    unsigned int u = __float_as_uint(v);
    unsigned int uh = (u + 0x7fffu + ((u >> 16) & 1u)) & 0xffff0000u;
    float lo = v - __uint_as_float(uh);
    thi[k * F + f] = (unsigned short)(uh >> 16);
    tlo[k * F + f] = bf16_rne(lo);
}

// ---------------- MFMA GEMM: C[N,K] = A[N,F] @ W[F,K] -----------------
// A fp32 (split to bf16 hi/lo in-kernel), W pre-split transposed [K][F].
// 128x128 tile, 4 waves, each 64x64 via 4x4 MFMA 16x16x32 tiles, BK=32.
// Requires K % 128 == 0, F % 32 == 0.

__global__ __launch_bounds__(256) void gemm_mfma(const float* __restrict__ A,
                                                 const unsigned short* __restrict__ Bthi,
                                                 const unsigned short* __restrict__ Btlo,
                                                 float* __restrict__ C,
                                                 int N, int F, int K) {
    __shared__ unsigned short As[2][128][40];  // [split][row m][k], 40 = 32 + 8 pad
    __shared__ unsigned short Bs[2][128][40];  // [split][col n][k]
    int tid = threadIdx.x;
    int lane = tid & 63, w = tid >> 6;
    int wr = (w >> 1) * 64, wc = (w & 1) * 64;
    int lr = lane & 15, lq = lane >> 4;
    int m0 = blockIdx.y * 128, n0 = blockIdx.x * 128;
    f32x4 acc[4][4] = {};

    for (int k0 = 0; k0 < F; k0 += 32) {
        __syncthreads();
        // stage A: fp32 -> split hi/lo.  128 rows x 8 float4-chunks = 1024 slots
#pragma unroll
        for (int i = 0; i < 4; ++i) {
            int slot = i * 256 + tid;
            int r = slot >> 3, c = slot & 7;
            int gr = m0 + r;
            float4 v = make_float4(0.f, 0.f, 0.f, 0.f);
            if (gr < N) v = *(const float4*)&A[(size_t)gr * F + k0 + c * 4];
            float vv[4] = {v.x, v.y, v.z, v.w};
            unsigned short h[4], l[4];
#pragma unroll
            for (int j = 0; j < 4; ++j) {
                unsigned int u = __float_as_uint(vv[j]);
                unsigned int uh = (u + 0x7fffu + ((u >> 16) & 1u)) & 0xffff0000u;
                h[j] = (unsigned short)(uh >> 16);
                l[j] = bf16_rne(vv[j] - __uint_as_float(uh));
            }
            *(ushort4*)&As[0][r][c * 4] = make_ushort4(h[0], h[1], h[2], h[3]);
            *(ushort4*)&As[1][r][c * 4] = make_ushort4(l[0], l[1], l[2], l[3]);
        }
        // stage B (pre-split bf16): 2 splits x 128 rows x 4 chunks(8 bf16) = 1024 slots
#pragma unroll
        for (int i = 0; i < 4; ++i) {
            int slot = i * 256 + tid;
            int s = slot >> 9, r = (slot >> 2) & 127, c = slot & 3;
            const unsigned short* B = s ? Btlo : Bthi;
            uint4 bv = *(const uint4*)&B[(size_t)(n0 + r) * F + k0 + c * 8];
            *(uint4*)&Bs[s][r][c * 8] = bv;
        }
        __syncthreads();

        v8s af[2][4], bf[2][4];
#pragma unroll
        for (int mt = 0; mt < 4; ++mt) {
            af[0][mt] = *(const v8s*)&As[0][wr + mt * 16 + lr][lq * 8];
            af[1][mt] = *(const v8s*)&As[1][wr + mt * 16 + lr][lq * 8];
        }
#pragma unroll
        for (int nt = 0; nt < 4; ++nt) {
            bf[0][nt] = *(const v8s*)&Bs[0][wc + nt * 16 + lr][lq * 8];
            bf[1][nt] = *(const v8s*)&Bs[1][wc + nt * 16 + lr][lq * 8];
        }
#pragma unroll
        for (int mt = 0; mt < 4; ++mt)
#pragma unroll
            for (int nt = 0; nt < 4; ++nt) {
                acc[mt][nt] = __builtin_amdgcn_mfma_f32_16x16x32_bf16(af[0][mt], bf[0][nt], acc[mt][nt], 0, 0, 0);
                acc[mt][nt] = __builtin_amdgcn_mfma_f32_16x16x32_bf16(af[0][mt], bf[1][nt], acc[mt][nt], 0, 0, 0);
                acc[mt][nt] = __builtin_amdgcn_mfma_f32_16x16x32_bf16(af[1][mt], bf[0][nt], acc[mt][nt], 0, 0, 0);
            }
    }
    // epilogue: C/D layout col = lane&15, row = (lane>>4)*4 + reg
#pragma unroll
    for (int mt = 0; mt < 4; ++mt) {
        int rbase = m0 + wr + mt * 16 + lq * 4;
#pragma unroll
        for (int nt = 0; nt < 4; ++nt) {
            int col = n0 + wc + nt * 16 + lr;
#pragma unroll
            for (int r = 0; r < 4; ++r) {
                int row = rbase + r;
                if (row < N) C[(size_t)row * K + col] = acc[mt][nt][r];
            }
        }
    }
}

// ---------------- fp32 GEMM (layer 2 only, K=16) ----------------

__global__ __launch_bounds__(256) void gemm_kernel(const float* __restrict__ A,
                                                   const float* __restrict__ W,
                                                   float* __restrict__ C,
                                                   int N, int F, int K) {
    __shared__ __align__(16) float As2[16][68];
    __shared__ __align__(16) float Ws2[16][64];
    int tid = threadIdx.x;
    int tx = tid & 15, ty = tid >> 4;
    int r0 = blockIdx.y * 64, c0 = blockIdx.x * 64;
    int arow = tid >> 2, akq = tid & 3;
    int wk = tid >> 4, wcq = tid & 15;
    float acc[4][4] = {};

    for (int k0 = 0; k0 < F; k0 += 16) {
        float4 av = make_float4(0.f, 0.f, 0.f, 0.f);
        int gr = r0 + arow;
        if (gr < N) av = *(const float4*)&A[(size_t)gr * F + k0 + akq * 4];
        float4 wv = make_float4(0.f, 0.f, 0.f, 0.f);
        int gc = c0 + wcq * 4;
        if (gc < K) wv = *(const float4*)&W[(size_t)(k0 + wk) * K + gc];
        __syncthreads();
        As2[akq * 4 + 0][arow] = av.x;
        As2[akq * 4 + 1][arow] = av.y;
        As2[akq * 4 + 2][arow] = av.z;
        As2[akq * 4 + 3][arow] = av.w;
        *(float4*)&Ws2[wk][wcq * 4] = wv;
        __syncthreads();
#pragma unroll
        for (int k = 0; k < 16; ++k) {
            float4 a = *(const float4*)&As2[k][ty * 4];
            float4 wv2 = *(const float4*)&Ws2[k][tx * 4];
            acc[0][0] += a.x * wv2.x; acc[0][1] += a.x * wv2.y; acc[0][2] += a.x * wv2.z; acc[0][3] += a.x * wv2.w;
            acc[1][0] += a.y * wv2.x; acc[1][1] += a.y * wv2.y; acc[1][2] += a.y * wv2.z; acc[1][3] += a.y * wv2.w;
            acc[2][0] += a.z * wv2.x; acc[2][1] += a.z * wv2.y; acc[2][2] += a.z * wv2.z; acc[2][3] += a.z * wv2.w;
            acc[3][0] += a.w * wv2.x; acc[3][1] += a.w * wv2.y; acc[3][2] += a.w * wv2.z; acc[3][3] += a.w * wv2.w;
        }
    }
#pragma unroll
    for (int i = 0; i < 4; ++i) {
        int gr = r0 + ty * 4 + i;
        if (gr < N && (c0 + tx * 4) < K) {
            float4 o4 = make_float4(acc[i][0], acc[i][1], acc[i][2], acc[i][3]);
            *(float4*)&C[(size_t)gr * K + c0 + tx * 4] = o4;
        }
    }
}

// ---------------- el/er + bf16 cast of feat ----------------

template <int H, int D>
__global__ __launch_bounds__(256) void elr_kernel(const float* __restrict__ feat,
                                                  const float* __restrict__ al,
                                                  const float* __restrict__ ar,
                                                  float* __restrict__ el,
                                                  float* __restrict__ er,
                                                  __hip_bfloat16* __restrict__ featb, int N) {
    constexpr int HD = H * D;
    constexpr int G = 256 / HD;
    int tid = threadIdx.x;
    int g = tid / HD;
    int rem = tid % HD;
    int h = rem / D;
    int d = rem % D;
    int n = blockIdx.x * G + g;
    float vl = 0.f, vr = 0.f;
    if (n < N) {
        float f = feat[(size_t)n * HD + rem];
        featb[(size_t)n * HD + rem] = __float2bfloat16(f);
        vl = f * al[rem];
        vr = f * ar[rem];
    }
#pragma unroll
    for (int o = D / 2; o >= 1; o >>= 1) {
        vl += __shfl_xor(vl, o);
        vr += __shfl_xor(vr, o);
    }
    if (n < N && d == 0) {
        el[n * H + h] = vl;
        er[n * H + h] = vr;
    }
}

// ---------------- per-node softmax + aggregation (bf16 gather) --------

template <int H, int D, int CAP, int U>
__global__ __launch_bounds__(H * 64) void agg_kernel(const __hip_bfloat16* __restrict__ featb,
                                                     const float* __restrict__ feat,
                                                     const float* __restrict__ el,
                                                     const float* __restrict__ er,
                                                     const float* __restrict__ bias,
                                                     const int* __restrict__ off,
                                                     const int* __restrict__ csr,
                                                     float* __restrict__ out, int N) {
    constexpr int HD = H * D;
    constexpr int L = D / 2;    // lanes per edge slot (bf16 pair per lane)
    constexpr int ES = 64 / L;  // edge slots per wave
    __shared__ float s_alpha[H][CAP];
    __shared__ int s_src[CAP];
    int n = blockIdx.x;
    int h = threadIdx.x >> 6;
    int lane = threadIdx.x & 63;
    int begin = off[n];
    int deg = off[n + 1] - begin;
    float er_nh = er[n * H + h];

    // Phase 1: e values + max
    float m = -INFINITY;
    for (int i = lane; i < deg; i += 64) {
        int s = csr[begin + i];
        if (h == 0 && i < CAP) s_src[i] = s;
        float e = el[s * H + h] + er_nh;
        e = e > 0.f ? e : NEG_SLOPE * e;
        if (i < CAP) s_alpha[h][i] = e;
        m = fmaxf(m, e);
    }
#pragma unroll
    for (int o = 32; o >= 1; o >>= 1) m = fmaxf(m, __shfl_xor(m, o));

    // Phase 2: exp + sum
    float ss = 0.f;
    for (int i = lane; i < deg; i += 64) {
        float e;
        if (i < CAP) e = s_alpha[h][i];
        else {
            int s = csr[begin + i];
            e = el[s * H + h] + er_nh;
            e = e > 0.f ? e : NEG_SLOPE * e;
        }
        float x = __expf(e - m);
        ss += x;
        if (i < CAP) s_alpha[h][i] = x;
    }
#pragma unroll
    for (int o = 32; o >= 1; o >>= 1) ss += __shfl_xor(ss, o);
    float inv = (deg > 0) ? 1.f / ss : 0.f;

    __syncthreads();  // s_src (wave 0) + s_alpha visible to all

    // Phase 3: aggregate over bf16 feat rows.
    int slot = lane / L;
    int p = lane % L;  // handles d = 2p, 2p+1
    int dcap = deg < CAP ? deg : CAP;
    const unsigned int* frow = (const unsigned int*)featb;
    size_t colOff = (size_t)(h * D) / 2 + p;
    float accx = 0.f, accy = 0.f;
    int j = slot;
    for (; j + (U - 1) * ES < dcap; j += U * ES) {
        float a[U];
        unsigned int f[U];
        int s[U];
#pragma unroll
        for (int u = 0; u < U; ++u) {
            int idx = j + u * ES;
            s[u] = s_src[idx];
            a[u] = s_alpha[h][idx];
        }
#pragma unroll
        for (int u = 0; u < U; ++u)
            f[u] = frow[(size_t)s[u] * (HD / 2) + colOff];
#pragma unroll
        for (int u = 0; u < U; ++u) {
            float lo = __uint_as_float(f[u] << 16);
            float hi = __uint_as_float(f[u] & 0xffff0000u);
            accx += a[u] * lo;
            accy += a[u] * hi;
        }
    }
    for (; j < dcap; j += ES) {
        float a = s_alpha[h][j];
        unsigned int f = frow[(size_t)s_src[j] * (HD / 2) + colOff];
        accx += a * __uint_as_float(f << 16);
        accy += a * __uint_as_float(f & 0xffff0000u);
    }
    // spill path (deg > CAP) — correctness only, fp32 feat
    for (int i = CAP + slot; i < deg; i += ES) {
        int s = csr[begin + i];
        float e = el[s * H + h] + er_nh;
        e = e > 0.f ? e : NEG_SLOPE * e;
        float wex = __expf(e - m);
        accx += wex * feat[(size_t)s * HD + h * D + 2 * p];
        accy += wex * feat[(size_t)s * HD + h * D + 2 * p + 1];
    }
#pragma unroll
    for (int o = L; o < 64; o <<= 1) {
        accx += __shfl_xor(accx, o);
        accy += __shfl_xor(accy, o);
    }
    if (lane < L) {
        float2 o2 = make_float2(accx * inv + bias[h * D + 2 * p],
                                accy * inv + bias[h * D + 2 * p + 1]);
        *(float2*)&out[(size_t)n * HD + h * D + 2 * p] = o2;
    }
}

// ---------------- launch ----------------

extern "C" void kernel_launch(void* const* d_in, const int* in_sizes, int n_in,
                              void* d_out, int out_size, void* d_ws, size_t ws_size,
                              hipStream_t stream) {
    const float* inputs = (const float*)d_in[0];
    const float* W0 = (const float*)d_in[1];
    const float* al0 = (const float*)d_in[2];
    const float* ar0 = (const float*)d_in[3];
    const float* b0 = (const float*)d_in[4];
    const float* W1 = (const float*)d_in[5];
    const float* al1 = (const float*)d_in[6];
    const float* ar1 = (const float*)d_in[7];
    const float* b1 = (const float*)d_in[8];
    const float* W2 = (const float*)d_in[9];
    const float* al2 = (const float*)d_in[10];
    const float* ar2 = (const float*)d_in[11];
    const float* b2 = (const float*)d_in[12];
    const int* src = (const int*)d_in[13];
    const int* dst = (const int*)d_in[14];

    const int IN_DIM = 128;
    const int N = in_sizes[0] / IN_DIM;  // 50000
    const int E = in_sizes[13];          // 800000
    float* out = (float*)d_out;

    char* base = (char*)d_ws;
    size_t o = 0;
    auto carve = [&](size_t bytes) -> void* {
        void* p = base + o;
        o += (bytes + 255) & ~(size_t)255;
        return p;
    };
    int* off = (int*)carve((size_t)(N + 1) * sizeof(int));
    int* cursor = (int*)carve((size_t)N * sizeof(int));
    int* chunkSum = (int*)carve(64 * sizeof(int));
    int* chunkOff = (int*)carve(64 * sizeof(int));
    int* csr = (int*)carve((size_t)E * sizeof(int));
    float* el = (float*)carve((size_t)N * 4 * sizeof(float));
    float* er = (float*)carve((size_t)N * 4 * sizeof(float));
    float* feat = (float*)carve((size_t)N * 256 * sizeof(float));
    float* hbuf = (float*)carve((size_t)N * 256 * sizeof(float));
    __hip_bfloat16* featb = (__hip_bfloat16*)carve((size_t)N * 256 * sizeof(__hip_bfloat16));
    unsigned short* wt0hi = (unsigned short*)carve((size_t)128 * 256 * sizeof(unsigned short));
    unsigned short* wt0lo = (unsigned short*)carve((size_t)128 * 256 * sizeof(unsigned short));
    unsigned short* wt1hi = (unsigned short*)carve((size_t)256 * 256 * sizeof(unsigned short));
    unsigned short* wt1lo = (unsigned short*)carve((size_t)256 * 256 * sizeof(unsigned short));

    // ---- CSR build ----
    hipMemsetAsync(off, 0, (size_t)(N + 1) * sizeof(int), stream);
    int egrid = (E + 255) / 256;
    count_deg<<<egrid, 256, 0, stream>>>(dst, off, E);
    int nchunks = (N + 2047) / 2048;
    scan_chunk<<<nchunks, 256, 0, stream>>>(off, chunkSum, N);
    scan_tail<<<1, 64, 0, stream>>>(chunkSum, chunkOff, nchunks, off, N, E);
    add_chunk_off<<<(N + 255) / 256, 256, 0, stream>>>(off, cursor, chunkOff, N);
    scatter_edges<<<egrid, 256, 0, stream>>>(src, dst, cursor, csr, E);

    // ---- W prep (split + transpose) ----
    wsplit<<<(128 * 256 + 255) / 256, 256, 0, stream>>>(W0, wt0hi, wt0lo, 128, 256);
    wsplit<<<(256 * 256 + 255) / 256, 256, 0, stream>>>(W1, wt1hi, wt1lo, 256, 256);

    // ---- Layer 0: 128 -> 4x64 (MFMA) ----
    {
        dim3 grid(256 / 128, (N + 127) / 128);
        gemm_mfma<<<grid, 256, 0, stream>>>(inputs, wt0hi, wt0lo, feat, N, 128, 256);
        elr_kernel<4, 64><<<N, 256, 0, stream>>>(feat, al0, ar0, el, er, featb, N);
        agg_kernel<4, 64, 512, 8><<<N, 256, 0, stream>>>(featb, feat, el, er, b0, off, csr, hbuf, N);
    }
    // ---- Layer 1: 256 -> 4x64 (MFMA) ----
    {
        dim3 grid(256 / 128, (N + 127) / 128);
        gemm_mfma<<<grid, 256, 0, stream>>>(hbuf, wt1hi, wt1lo, feat, N, 256, 256);
        elr_kernel<4, 64><<<N, 256, 0, stream>>>(feat, al1, ar1, el, er, featb, N);
        agg_kernel<4, 64, 512, 8><<<N, 256, 0, stream>>>(featb, feat, el, er, b1, off, csr, hbuf, N);
    }
    // ---- Layer 2: 256 -> 1x16 (fp32 vector GEMM, tiny) ----
    {
        dim3 grid((16 + 63) / 64, (N + 63) / 64);
        gemm_kernel<<<grid, 256, 0, stream>>>(hbuf, W2, feat, N, 256, 16);
        elr_kernel<1, 16><<<(N + 15) / 16, 256, 0, stream>>>(feat, al2, ar2, el, er, featb, N);
        agg_kernel<1, 16, 512, 2><<<N, 64, 0, stream>>>(featb, feat, el, er, b2, off, csr, out, N);
    }
}

// Round 5
// 531.802 us; speedup vs baseline: 1.7094x; 1.1114x over previous
//
#include <hip/hip_runtime.h>
#include <hip/hip_bf16.h>
#include <math.h>

// ---------------------------------------------------------------------------
// GAT 3-layer forward.
// R5 change: agg for H=4,D=64 rewritten as wave-per-node (all 4 heads in one
// wave): float4 el gather, full-row coalesced bf16 gathers (512B/edge),
// no cross-wave sync, no cross-lane reduce in the aggregation, coalesced
// float2 stores. ~3x fewer VALU instructions than the wave-per-head version.
// ---------------------------------------------------------------------------

#define NEG_SLOPE 0.2f

typedef __attribute__((ext_vector_type(8))) short v8s;   // 8 bf16 in 4 VGPRs
typedef __attribute__((ext_vector_type(4))) float f32x4;

// ---------------- CSR build ----------------

__global__ __launch_bounds__(256) void count_deg(const int* __restrict__ dst,
                                                 int* __restrict__ deg, int E) {
    int e = blockIdx.x * 256 + threadIdx.x;
    if (e < E) atomicAdd(&deg[dst[e]], 1);
}

__global__ __launch_bounds__(256) void scan_chunk(int* __restrict__ off,
                                                  int* __restrict__ chunkSum, int N) {
    __shared__ int sdata[256];
    int tid = threadIdx.x;
    int base = blockIdx.x * 2048 + tid * 8;
    int v[8];
    int tsum = 0;
#pragma unroll
    for (int j = 0; j < 8; ++j) {
        int idx = base + j;
        v[j] = (idx < N) ? off[idx] : 0;
        tsum += v[j];
    }
    sdata[tid] = tsum;
    __syncthreads();
    for (int o = 1; o < 256; o <<= 1) {
        int t = (tid >= o) ? sdata[tid - o] : 0;
        __syncthreads();
        sdata[tid] += t;
        __syncthreads();
    }
    int run = sdata[tid] - tsum;
#pragma unroll
    for (int j = 0; j < 8; ++j) {
        int idx = base + j;
        if (idx < N) off[idx] = run;
        run += v[j];
    }
    if (tid == 255) chunkSum[blockIdx.x] = sdata[255];
}

__global__ void scan_tail(const int* __restrict__ chunkSum, int* __restrict__ chunkOff,
                          int nchunks, int* __restrict__ off, int N, int E) {
    if (threadIdx.x == 0 && blockIdx.x == 0) {
        int run = 0;
        for (int c = 0; c < nchunks; ++c) { chunkOff[c] = run; run += chunkSum[c]; }
        off[N] = E;
    }
}

__global__ __launch_bounds__(256) void add_chunk_off(int* __restrict__ off,
                                                     int* __restrict__ cursor,
                                                     const int* __restrict__ chunkOff, int N) {
    int i = blockIdx.x * 256 + threadIdx.x;
    if (i < N) {
        int v = off[i] + chunkOff[i >> 11];
        off[i] = v;
        cursor[i] = v;
    }
}

__global__ __launch_bounds__(256) void scatter_edges(const int* __restrict__ src,
                                                     const int* __restrict__ dst,
                                                     int* __restrict__ cursor,
                                                     int* __restrict__ csr, int E) {
    int e = blockIdx.x * 256 + threadIdx.x;
    if (e < E) {
        int d = dst[e];
        int pos = atomicAdd(&cursor[d], 1);
        csr[pos] = src[e];
    }
}

// ---------------- bf16 split helpers ----------------

__device__ __forceinline__ unsigned short bf16_rne(float x) {
    unsigned int u = __float_as_uint(x);
    return (unsigned short)((u + 0x7fffu + ((u >> 16) & 1u)) >> 16);
}

// W prep: read W[F][K] fp32, write Wt_hi/Wt_lo as [K][F] bf16 (transposed).
__global__ __launch_bounds__(256) void wsplit(const float* __restrict__ W,
                                              unsigned short* __restrict__ thi,
                                              unsigned short* __restrict__ tlo,
                                              int F, int K) {
    int idx = blockIdx.x * 256 + threadIdx.x;
    if (idx >= F * K) return;
    int f = idx / K, k = idx % K;
    float v = W[idx];
    unsigned int u = __float_as_uint(v);
    unsigned int uh = (u + 0x7fffu + ((u >> 16) & 1u)) & 0xffff0000u;
    float lo = v - __uint_as_float(uh);
    thi[k * F + f] = (unsigned short)(uh >> 16);
    tlo[k * F + f] = bf16_rne(lo);
}

// ---------------- MFMA GEMM: C[N,K] = A[N,F] @ W[F,K] -----------------
// Split-bf16 3-term. 128x128 tile, 4 waves, BK=32.

__global__ __launch_bounds__(256) void gemm_mfma(const float* __restrict__ A,
                                                 const unsigned short* __restrict__ Bthi,
                                                 const unsigned short* __restrict__ Btlo,
                                                 float* __restrict__ C,
                                                 int N, int F, int K) {
    __shared__ unsigned short As[2][128][40];
    __shared__ unsigned short Bs[2][128][40];
    int tid = threadIdx.x;
    int lane = tid & 63, w = tid >> 6;
    int wr = (w >> 1) * 64, wc = (w & 1) * 64;
    int lr = lane & 15, lq = lane >> 4;
    int m0 = blockIdx.y * 128, n0 = blockIdx.x * 128;
    f32x4 acc[4][4] = {};

    for (int k0 = 0; k0 < F; k0 += 32) {
        __syncthreads();
#pragma unroll
        for (int i = 0; i < 4; ++i) {
            int slot = i * 256 + tid;
            int r = slot >> 3, c = slot & 7;
            int gr = m0 + r;
            float4 v = make_float4(0.f, 0.f, 0.f, 0.f);
            if (gr < N) v = *(const float4*)&A[(size_t)gr * F + k0 + c * 4];
            float vv[4] = {v.x, v.y, v.z, v.w};
            unsigned short h[4], l[4];
#pragma unroll
            for (int j = 0; j < 4; ++j) {
                unsigned int u = __float_as_uint(vv[j]);
                unsigned int uh = (u + 0x7fffu + ((u >> 16) & 1u)) & 0xffff0000u;
                h[j] = (unsigned short)(uh >> 16);
                l[j] = bf16_rne(vv[j] - __uint_as_float(uh));
            }
            *(ushort4*)&As[0][r][c * 4] = make_ushort4(h[0], h[1], h[2], h[3]);
            *(ushort4*)&As[1][r][c * 4] = make_ushort4(l[0], l[1], l[2], l[3]);
        }
#pragma unroll
        for (int i = 0; i < 4; ++i) {
            int slot = i * 256 + tid;
            int s = slot >> 9, r = (slot >> 2) & 127, c = slot & 3;
            const unsigned short* B = s ? Btlo : Bthi;
            uint4 bv = *(const uint4*)&B[(size_t)(n0 + r) * F + k0 + c * 8];
            *(uint4*)&Bs[s][r][c * 8] = bv;
        }
        __syncthreads();

        v8s af[2][4], bf[2][4];
#pragma unroll
        for (int mt = 0; mt < 4; ++mt) {
            af[0][mt] = *(const v8s*)&As[0][wr + mt * 16 + lr][lq * 8];
            af[1][mt] = *(const v8s*)&As[1][wr + mt * 16 + lr][lq * 8];
        }
#pragma unroll
        for (int nt = 0; nt < 4; ++nt) {
            bf[0][nt] = *(const v8s*)&Bs[0][wc + nt * 16 + lr][lq * 8];
            bf[1][nt] = *(const v8s*)&Bs[1][wc + nt * 16 + lr][lq * 8];
        }
#pragma unroll
        for (int mt = 0; mt < 4; ++mt)
#pragma unroll
            for (int nt = 0; nt < 4; ++nt) {
                acc[mt][nt] = __builtin_amdgcn_mfma_f32_16x16x32_bf16(af[0][mt], bf[0][nt], acc[mt][nt], 0, 0, 0);
                acc[mt][nt] = __builtin_amdgcn_mfma_f32_16x16x32_bf16(af[0][mt], bf[1][nt], acc[mt][nt], 0, 0, 0);
                acc[mt][nt] = __builtin_amdgcn_mfma_f32_16x16x32_bf16(af[1][mt], bf[0][nt], acc[mt][nt], 0, 0, 0);
            }
    }
#pragma unroll
    for (int mt = 0; mt < 4; ++mt) {
        int rbase = m0 + wr + mt * 16 + lq * 4;
#pragma unroll
        for (int nt = 0; nt < 4; ++nt) {
            int col = n0 + wc + nt * 16 + lr;
#pragma unroll
            for (int r = 0; r < 4; ++r) {
                int row = rbase + r;
                if (row < N) C[(size_t)row * K + col] = acc[mt][nt][r];
            }
        }
    }
}

// ---------------- fp32 GEMM (layer 2 only, K=16) ----------------

__global__ __launch_bounds__(256) void gemm_kernel(const float* __restrict__ A,
                                                   const float* __restrict__ W,
                                                   float* __restrict__ C,
                                                   int N, int F, int K) {
    __shared__ __align__(16) float As2[16][68];
    __shared__ __align__(16) float Ws2[16][64];
    int tid = threadIdx.x;
    int tx = tid & 15, ty = tid >> 4;
    int r0 = blockIdx.y * 64, c0 = blockIdx.x * 64;
    int arow = tid >> 2, akq = tid & 3;
    int wk = tid >> 4, wcq = tid & 15;
    float acc[4][4] = {};

    for (int k0 = 0; k0 < F; k0 += 16) {
        float4 av = make_float4(0.f, 0.f, 0.f, 0.f);
        int gr = r0 + arow;
        if (gr < N) av = *(const float4*)&A[(size_t)gr * F + k0 + akq * 4];
        float4 wv = make_float4(0.f, 0.f, 0.f, 0.f);
        int gc = c0 + wcq * 4;
        if (gc < K) wv = *(const float4*)&W[(size_t)(k0 + wk) * K + gc];
        __syncthreads();
        As2[akq * 4 + 0][arow] = av.x;
        As2[akq * 4 + 1][arow] = av.y;
        As2[akq * 4 + 2][arow] = av.z;
        As2[akq * 4 + 3][arow] = av.w;
        *(float4*)&Ws2[wk][wcq * 4] = wv;
        __syncthreads();
#pragma unroll
        for (int k = 0; k < 16; ++k) {
            float4 a = *(const float4*)&As2[k][ty * 4];
            float4 wv2 = *(const float4*)&Ws2[k][tx * 4];
            acc[0][0] += a.x * wv2.x; acc[0][1] += a.x * wv2.y; acc[0][2] += a.x * wv2.z; acc[0][3] += a.x * wv2.w;
            acc[1][0] += a.y * wv2.x; acc[1][1] += a.y * wv2.y; acc[1][2] += a.y * wv2.z; acc[1][3] += a.y * wv2.w;
            acc[2][0] += a.z * wv2.x; acc[2][1] += a.z * wv2.y; acc[2][2] += a.z * wv2.z; acc[2][3] += a.z * wv2.w;
            acc[3][0] += a.w * wv2.x; acc[3][1] += a.w * wv2.y; acc[3][2] += a.w * wv2.z; acc[3][3] += a.w * wv2.w;
        }
    }
#pragma unroll
    for (int i = 0; i < 4; ++i) {
        int gr = r0 + ty * 4 + i;
        if (gr < N && (c0 + tx * 4) < K) {
            float4 o4 = make_float4(acc[i][0], acc[i][1], acc[i][2], acc[i][3]);
            *(float4*)&C[(size_t)gr * K + c0 + tx * 4] = o4;
        }
    }
}

// ---------------- el/er + bf16 cast of feat ----------------

template <int H, int D>
__global__ __launch_bounds__(256) void elr_kernel(const float* __restrict__ feat,
                                                  const float* __restrict__ al,
                                                  const float* __restrict__ ar,
                                                  float* __restrict__ el,
                                                  float* __restrict__ er,
                                                  __hip_bfloat16* __restrict__ featb, int N) {
    constexpr int HD = H * D;
    constexpr int G = 256 / HD;
    int tid = threadIdx.x;
    int g = tid / HD;
    int rem = tid % HD;
    int h = rem / D;
    int d = rem % D;
    int n = blockIdx.x * G + g;
    float vl = 0.f, vr = 0.f;
    if (n < N) {
        float f = feat[(size_t)n * HD + rem];
        featb[(size_t)n * HD + rem] = __float2bfloat16(f);
        vl = f * al[rem];
        vr = f * ar[rem];
    }
#pragma unroll
    for (int o = D / 2; o >= 1; o >>= 1) {
        vl += __shfl_xor(vl, o);
        vr += __shfl_xor(vr, o);
    }
    if (n < N && d == 0) {
        el[n * H + h] = vl;
        er[n * H + h] = vr;
    }
}

// ---------------- agg for H=4, D=64: wave-per-node ----------------
// Each wave handles one node, all 4 heads. Block = 4 waves = 4 nodes.
// No __syncthreads (each wave owns its LDS slice).
// Phase 1: lane=edge, float4 el gather, leaky-relu, e -> LDS (head-major),
//          per-head wave max.
// Phase 2: exp(e-m) via LDS, per-head sums.
// Phase 3: per edge read the whole 512B bf16 row coalesced (2 uints/lane);
//          lane p covers cols {2p,2p+1} (head p>>5) and {128+2p,129+2p}
//          (head 2+(p>>5)); alpha via LDS broadcast; unroll U.

template <int CAP, int U>
__global__ __launch_bounds__(256) void agg4_kernel(const __hip_bfloat16* __restrict__ featb,
                                                   const float* __restrict__ feat,
                                                   const float* __restrict__ el,
                                                   const float* __restrict__ er,
                                                   const float* __restrict__ bias,
                                                   const int* __restrict__ off,
                                                   const int* __restrict__ csr,
                                                   float* __restrict__ out, int N) {
    __shared__ float s_alpha[4][4][CAP];  // [wave][head][edge]
    __shared__ int s_src[4][CAP];
    int w = threadIdx.x >> 6;
    int lane = threadIdx.x & 63;
    int n = blockIdx.x * 4 + w;
    if (n >= N) return;
    int begin = off[n];
    int deg = off[n + 1] - begin;
    float4 ern = *(const float4*)&er[(size_t)n * 4];

    // Phase 1
    float m0 = -INFINITY, m1 = -INFINITY, m2 = -INFINITY, m3 = -INFINITY;
    for (int i = lane; i < deg; i += 64) {
        int s = csr[begin + i];
        float4 e = *(const float4*)&el[(size_t)s * 4];
        e.x += ern.x; e.y += ern.y; e.z += ern.z; e.w += ern.w;
        e.x = e.x > 0.f ? e.x : NEG_SLOPE * e.x;
        e.y = e.y > 0.f ? e.y : NEG_SLOPE * e.y;
        e.z = e.z > 0.f ? e.z : NEG_SLOPE * e.z;
        e.w = e.w > 0.f ? e.w : NEG_SLOPE * e.w;
        if (i < CAP) {
            s_src[w][i] = s;
            s_alpha[w][0][i] = e.x;
            s_alpha[w][1][i] = e.y;
            s_alpha[w][2][i] = e.z;
            s_alpha[w][3][i] = e.w;
        }
        m0 = fmaxf(m0, e.x); m1 = fmaxf(m1, e.y);
        m2 = fmaxf(m2, e.z); m3 = fmaxf(m3, e.w);
    }
#pragma unroll
    for (int o = 32; o >= 1; o >>= 1) {
        m0 = fmaxf(m0, __shfl_xor(m0, o));
        m1 = fmaxf(m1, __shfl_xor(m1, o));
        m2 = fmaxf(m2, __shfl_xor(m2, o));
        m3 = fmaxf(m3, __shfl_xor(m3, o));
    }

    // Phase 2
    float s0 = 0.f, s1 = 0.f, s2 = 0.f, s3 = 0.f;
    for (int i = lane; i < deg; i += 64) {
        float e0, e1, e2, e3;
        if (i < CAP) {
            e0 = s_alpha[w][0][i]; e1 = s_alpha[w][1][i];
            e2 = s_alpha[w][2][i]; e3 = s_alpha[w][3][i];
        } else {
            int s = csr[begin + i];
            float4 e = *(const float4*)&el[(size_t)s * 4];
            e0 = e.x + ern.x; e1 = e.y + ern.y; e2 = e.z + ern.z; e3 = e.w + ern.w;
            e0 = e0 > 0.f ? e0 : NEG_SLOPE * e0;
            e1 = e1 > 0.f ? e1 : NEG_SLOPE * e1;
            e2 = e2 > 0.f ? e2 : NEG_SLOPE * e2;
            e3 = e3 > 0.f ? e3 : NEG_SLOPE * e3;
        }
        e0 = __expf(e0 - m0); e1 = __expf(e1 - m1);
        e2 = __expf(e2 - m2); e3 = __expf(e3 - m3);
        if (i < CAP) {
            s_alpha[w][0][i] = e0; s_alpha[w][1][i] = e1;
            s_alpha[w][2][i] = e2; s_alpha[w][3][i] = e3;
        }
        s0 += e0; s1 += e1; s2 += e2; s3 += e3;
    }
#pragma unroll
    for (int o = 32; o >= 1; o >>= 1) {
        s0 += __shfl_xor(s0, o); s1 += __shfl_xor(s1, o);
        s2 += __shfl_xor(s2, o); s3 += __shfl_xor(s3, o);
    }
    float inv0 = deg > 0 ? 1.f / s0 : 0.f;
    float inv1 = deg > 0 ? 1.f / s1 : 0.f;
    float inv2 = deg > 0 ? 1.f / s2 : 0.f;
    float inv3 = deg > 0 ? 1.f / s3 : 0.f;

    // Phase 3
    int hsel = lane >> 5;  // 0: heads {0,2}; 1: heads {1,3}
    int dcap = deg < CAP ? deg : CAP;
    const unsigned int* frow = (const unsigned int*)featb;
    float a0 = 0.f, a1 = 0.f, a2 = 0.f, a3 = 0.f;
    int j = 0;
    for (; j + U <= dcap; j += U) {
        int s[U];
        unsigned int f0[U], f1[U];
        float aA[U], aB[U];
#pragma unroll
        for (int u = 0; u < U; ++u) s[u] = s_src[w][j + u];
#pragma unroll
        for (int u = 0; u < U; ++u) {
            const unsigned int* rp = frow + (size_t)s[u] * 128;
            f0[u] = rp[lane];
            f1[u] = rp[64 + lane];
        }
#pragma unroll
        for (int u = 0; u < U; ++u) {
            aA[u] = s_alpha[w][hsel][j + u];
            aB[u] = s_alpha[w][2 + hsel][j + u];
        }
#pragma unroll
        for (int u = 0; u < U; ++u) {
            a0 += aA[u] * __uint_as_float(f0[u] << 16);
            a1 += aA[u] * __uint_as_float(f0[u] & 0xffff0000u);
            a2 += aB[u] * __uint_as_float(f1[u] << 16);
            a3 += aB[u] * __uint_as_float(f1[u] & 0xffff0000u);
        }
    }
    for (; j < dcap; ++j) {
        int s = s_src[w][j];
        const unsigned int* rp = frow + (size_t)s * 128;
        unsigned int f0v = rp[lane], f1v = rp[64 + lane];
        float aA = s_alpha[w][hsel][j], aB = s_alpha[w][2 + hsel][j];
        a0 += aA * __uint_as_float(f0v << 16);
        a1 += aA * __uint_as_float(f0v & 0xffff0000u);
        a2 += aB * __uint_as_float(f1v << 16);
        a3 += aB * __uint_as_float(f1v & 0xffff0000u);
    }
    // spill path deg > CAP (correctness only)
    for (int i = CAP; i < deg; ++i) {
        int s = csr[begin + i];
        float4 e = *(const float4*)&el[(size_t)s * 4];
        float e0 = e.x + ern.x, e1 = e.y + ern.y, e2 = e.z + ern.z, e3 = e.w + ern.w;
        e0 = e0 > 0.f ? e0 : NEG_SLOPE * e0;
        e1 = e1 > 0.f ? e1 : NEG_SLOPE * e1;
        e2 = e2 > 0.f ? e2 : NEG_SLOPE * e2;
        e3 = e3 > 0.f ? e3 : NEG_SLOPE * e3;
        float x0 = __expf(e0 - m0), x1 = __expf(e1 - m1);
        float x2 = __expf(e2 - m2), x3 = __expf(e3 - m3);
        float aA = hsel ? x1 : x0, aB = hsel ? x3 : x2;
        const float* fp = feat + (size_t)s * 256;
        a0 += aA * fp[2 * lane];
        a1 += aA * fp[2 * lane + 1];
        a2 += aB * fp[128 + 2 * lane];
        a3 += aB * fp[128 + 2 * lane + 1];
    }
    float invA = hsel ? inv1 : inv0;
    float invB = hsel ? inv3 : inv2;
    float2 o0 = make_float2(a0 * invA + bias[2 * lane], a1 * invA + bias[2 * lane + 1]);
    float2 o1 = make_float2(a2 * invB + bias[128 + 2 * lane], a3 * invB + bias[128 + 2 * lane + 1]);
    *(float2*)&out[(size_t)n * 256 + 2 * lane] = o0;
    *(float2*)&out[(size_t)n * 256 + 128 + 2 * lane] = o1;
}

// ---------------- agg for H=1, D=16 (layer 2) ----------------

template <int H, int D, int CAP, int U>
__global__ __launch_bounds__(H * 64) void agg_kernel(const __hip_bfloat16* __restrict__ featb,
                                                     const float* __restrict__ feat,
                                                     const float* __restrict__ el,
                                                     const float* __restrict__ er,
                                                     const float* __restrict__ bias,
                                                     const int* __restrict__ off,
                                                     const int* __restrict__ csr,
                                                     float* __restrict__ out, int N) {
    constexpr int HD = H * D;
    constexpr int L = D / 2;
    constexpr int ES = 64 / L;
    __shared__ float s_alpha[H][CAP];
    __shared__ int s_src[CAP];
    int n = blockIdx.x;
    int h = threadIdx.x >> 6;
    int lane = threadIdx.x & 63;
    int begin = off[n];
    int deg = off[n + 1] - begin;
    float er_nh = er[n * H + h];

    float m = -INFINITY;
    for (int i = lane; i < deg; i += 64) {
        int s = csr[begin + i];
        if (h == 0 && i < CAP) s_src[i] = s;
        float e = el[s * H + h] + er_nh;
        e = e > 0.f ? e : NEG_SLOPE * e;
        if (i < CAP) s_alpha[h][i] = e;
        m = fmaxf(m, e);
    }
#pragma unroll
    for (int o = 32; o >= 1; o >>= 1) m = fmaxf(m, __shfl_xor(m, o));

    float ss = 0.f;
    for (int i = lane; i < deg; i += 64) {
        float e;
        if (i < CAP) e = s_alpha[h][i];
        else {
            int s = csr[begin + i];
            e = el[s * H + h] + er_nh;
            e = e > 0.f ? e : NEG_SLOPE * e;
        }
        float x = __expf(e - m);
        ss += x;
        if (i < CAP) s_alpha[h][i] = x;
    }
#pragma unroll
    for (int o = 32; o >= 1; o >>= 1) ss += __shfl_xor(ss, o);
    float inv = (deg > 0) ? 1.f / ss : 0.f;

    __syncthreads();

    int slot = lane / L;
    int p = lane % L;
    int dcap = deg < CAP ? deg : CAP;
    const unsigned int* frow = (const unsigned int*)featb;
    size_t colOff = (size_t)(h * D) / 2 + p;
    float accx = 0.f, accy = 0.f;
    int j = slot;
    for (; j + (U - 1) * ES < dcap; j += U * ES) {
        float a[U];
        unsigned int f[U];
        int s[U];
#pragma unroll
        for (int u = 0; u < U; ++u) {
            int idx = j + u * ES;
            s[u] = s_src[idx];
            a[u] = s_alpha[h][idx];
        }
#pragma unroll
        for (int u = 0; u < U; ++u)
            f[u] = frow[(size_t)s[u] * (HD / 2) + colOff];
#pragma unroll
        for (int u = 0; u < U; ++u) {
            accx += a[u] * __uint_as_float(f[u] << 16);
            accy += a[u] * __uint_as_float(f[u] & 0xffff0000u);
        }
    }
    for (; j < dcap; j += ES) {
        float a = s_alpha[h][j];
        unsigned int f = frow[(size_t)s_src[j] * (HD / 2) + colOff];
        accx += a * __uint_as_float(f << 16);
        accy += a * __uint_as_float(f & 0xffff0000u);
    }
    for (int i = CAP + slot; i < deg; i += ES) {
        int s = csr[begin + i];
        float e = el[s * H + h] + er_nh;
        e = e > 0.f ? e : NEG_SLOPE * e;
        float wex = __expf(e - m);
        accx += wex * feat[(size_t)s * HD + h * D + 2 * p];
        accy += wex * feat[(size_t)s * HD + h * D + 2 * p + 1];
    }
#pragma unroll
    for (int o = L; o < 64; o <<= 1) {
        accx += __shfl_xor(accx, o);
        accy += __shfl_xor(accy, o);
    }
    if (lane < L) {
        float2 o2 = make_float2(accx * inv + bias[h * D + 2 * p],
                                accy * inv + bias[h * D + 2 * p + 1]);
        *(float2*)&out[(size_t)n * HD + h * D + 2 * p] = o2;
    }
}

// ---------------- launch ----------------

extern "C" void kernel_launch(void* const* d_in, const int* in_sizes, int n_in,
                              void* d_out, int out_size, void* d_ws, size_t ws_size,
                              hipStream_t stream) {
    const float* inputs = (const float*)d_in[0];
    const float* W0 = (const float*)d_in[1];
    const float* al0 = (const float*)d_in[2];
    const float* ar0 = (const float*)d_in[3];
    const float* b0 = (const float*)d_in[4];
    const float* W1 = (const float*)d_in[5];
    const float* al1 = (const float*)d_in[6];
    const float* ar1 = (const float*)d_in[7];
    const float* b1 = (const float*)d_in[8];
    const float* W2 = (const float*)d_in[9];
    const float* al2 = (const float*)d_in[10];
    const float* ar2 = (const float*)d_in[11];
    const float* b2 = (const float*)d_in[12];
    const int* src = (const int*)d_in[13];
    const int* dst = (const int*)d_in[14];

    const int IN_DIM = 128;
    const int N = in_sizes[0] / IN_DIM;  // 50000
    const int E = in_sizes[13];          // 800000
    float* out = (float*)d_out;

    char* base = (char*)d_ws;
    size_t o = 0;
    auto carve = [&](size_t bytes) -> void* {
        void* p = base + o;
        o += (bytes + 255) & ~(size_t)255;
        return p;
    };
    int* off = (int*)carve((size_t)(N + 1) * sizeof(int));
    int* cursor = (int*)carve((size_t)N * sizeof(int));
    int* chunkSum = (int*)carve(64 * sizeof(int));
    int* chunkOff = (int*)carve(64 * sizeof(int));
    int* csr = (int*)carve((size_t)E * sizeof(int));
    float* el = (float*)carve((size_t)N * 4 * sizeof(float));
    float* er = (float*)carve((size_t)N * 4 * sizeof(float));
    float* feat = (float*)carve((size_t)N * 256 * sizeof(float));
    float* hbuf = (float*)carve((size_t)N * 256 * sizeof(float));
    __hip_bfloat16* featb = (__hip_bfloat16*)carve((size_t)N * 256 * sizeof(__hip_bfloat16));
    unsigned short* wt0hi = (unsigned short*)carve((size_t)128 * 256 * sizeof(unsigned short));
    unsigned short* wt0lo = (unsigned short*)carve((size_t)128 * 256 * sizeof(unsigned short));
    unsigned short* wt1hi = (unsigned short*)carve((size_t)256 * 256 * sizeof(unsigned short));
    unsigned short* wt1lo = (unsigned short*)carve((size_t)256 * 256 * sizeof(unsigned short));

    // ---- CSR build ----
    hipMemsetAsync(off, 0, (size_t)(N + 1) * sizeof(int), stream);
    int egrid = (E + 255) / 256;
    count_deg<<<egrid, 256, 0, stream>>>(dst, off, E);
    int nchunks = (N + 2047) / 2048;
    scan_chunk<<<nchunks, 256, 0, stream>>>(off, chunkSum, N);
    scan_tail<<<1, 64, 0, stream>>>(chunkSum, chunkOff, nchunks, off, N, E);
    add_chunk_off<<<(N + 255) / 256, 256, 0, stream>>>(off, cursor, chunkOff, N);
    scatter_edges<<<egrid, 256, 0, stream>>>(src, dst, cursor, csr, E);

    // ---- W prep (split + transpose) ----
    wsplit<<<(128 * 256 + 255) / 256, 256, 0, stream>>>(W0, wt0hi, wt0lo, 128, 256);
    wsplit<<<(256 * 256 + 255) / 256, 256, 0, stream>>>(W1, wt1hi, wt1lo, 256, 256);

    // ---- Layer 0: 128 -> 4x64 (MFMA) ----
    {
        dim3 grid(256 / 128, (N + 127) / 128);
        gemm_mfma<<<grid, 256, 0, stream>>>(inputs, wt0hi, wt0lo, feat, N, 128, 256);
        elr_kernel<4, 64><<<N, 256, 0, stream>>>(feat, al0, ar0, el, er, featb, N);
        agg4_kernel<128, 8><<<(N + 3) / 4, 256, 0, stream>>>(featb, feat, el, er, b0, off, csr, hbuf, N);
    }
    // ---- Layer 1: 256 -> 4x64 (MFMA) ----
    {
        dim3 grid(256 / 128, (N + 127) / 128);
        gemm_mfma<<<grid, 256, 0, stream>>>(hbuf, wt1hi, wt1lo, feat, N, 256, 256);
        elr_kernel<4, 64><<<N, 256, 0, stream>>>(feat, al1, ar1, el, er, featb, N);
        agg4_kernel<128, 8><<<(N + 3) / 4, 256, 0, stream>>>(featb, feat, el, er, b1, off, csr, hbuf, N);
    }
    // ---- Layer 2: 256 -> 1x16 (fp32 vector GEMM, tiny) ----
    {
        dim3 grid((16 + 63) / 64, (N + 63) / 64);
        gemm_kernel<<<grid, 256, 0, stream>>>(hbuf, W2, feat, N, 256, 16);
        elr_kernel<1, 16><<<(N + 15) / 16, 256, 0, stream>>>(feat, al2, ar2, el, er, featb, N);
        agg_kernel<1, 16, 512, 2><<<N, 64, 0, stream>>>(featb, feat, el, er, b2, off, csr, out, N);
    }
}

// Round 6
// 489.301 us; speedup vs baseline: 1.8578x; 1.0869x over previous
//
#include <hip/hip_runtime.h>
#include <hip/hip_bf16.h>
#include <math.h>

// ---------------------------------------------------------------------------
// GAT 3-layer forward.
// R6 changes:
//  - gemm_mfma epilogue fused: computes el/er (shuffle-reduce, each wave owns
//    one head x 64 rows) and writes feat directly as bf16. elr<4,64> and the
//    fp32 feat array are gone for layers 0/1.
//  - agg4 softmax single pass for deg<=64 (e in registers, max+exp+sum in one
//    sweep); slow-loop fallback for deg>64.
//  - agg4 CAP 128->64 (LDS 10->5 KB) for 2x resident blocks.
// ---------------------------------------------------------------------------

#define NEG_SLOPE 0.2f

typedef __attribute__((ext_vector_type(8))) short v8s;   // 8 bf16 in 4 VGPRs
typedef __attribute__((ext_vector_type(4))) float f32x4;

// ---------------- CSR build ----------------

__global__ __launch_bounds__(256) void count_deg(const int* __restrict__ dst,
                                                 int* __restrict__ deg, int E) {
    int e = blockIdx.x * 256 + threadIdx.x;
    if (e < E) atomicAdd(&deg[dst[e]], 1);
}

__global__ __launch_bounds__(256) void scan_chunk(int* __restrict__ off,
                                                  int* __restrict__ chunkSum, int N) {
    __shared__ int sdata[256];
    int tid = threadIdx.x;
    int base = blockIdx.x * 2048 + tid * 8;
    int v[8];
    int tsum = 0;
#pragma unroll
    for (int j = 0; j < 8; ++j) {
        int idx = base + j;
        v[j] = (idx < N) ? off[idx] : 0;
        tsum += v[j];
    }
    sdata[tid] = tsum;
    __syncthreads();
    for (int o = 1; o < 256; o <<= 1) {
        int t = (tid >= o) ? sdata[tid - o] : 0;
        __syncthreads();
        sdata[tid] += t;
        __syncthreads();
    }
    int run = sdata[tid] - tsum;
#pragma unroll
    for (int j = 0; j < 8; ++j) {
        int idx = base + j;
        if (idx < N) off[idx] = run;
        run += v[j];
    }
    if (tid == 255) chunkSum[blockIdx.x] = sdata[255];
}

__global__ void scan_tail(const int* __restrict__ chunkSum, int* __restrict__ chunkOff,
                          int nchunks, int* __restrict__ off, int N, int E) {
    if (threadIdx.x == 0 && blockIdx.x == 0) {
        int run = 0;
        for (int c = 0; c < nchunks; ++c) { chunkOff[c] = run; run += chunkSum[c]; }
        off[N] = E;
    }
}

__global__ __launch_bounds__(256) void add_chunk_off(int* __restrict__ off,
                                                     int* __restrict__ cursor,
                                                     const int* __restrict__ chunkOff, int N) {
    int i = blockIdx.x * 256 + threadIdx.x;
    if (i < N) {
        int v = off[i] + chunkOff[i >> 11];
        off[i] = v;
        cursor[i] = v;
    }
}

__global__ __launch_bounds__(256) void scatter_edges(const int* __restrict__ src,
                                                     const int* __restrict__ dst,
                                                     int* __restrict__ cursor,
                                                     int* __restrict__ csr, int E) {
    int e = blockIdx.x * 256 + threadIdx.x;
    if (e < E) {
        int d = dst[e];
        int pos = atomicAdd(&cursor[d], 1);
        csr[pos] = src[e];
    }
}

// ---------------- bf16 split helpers ----------------

__device__ __forceinline__ unsigned short bf16_rne(float x) {
    unsigned int u = __float_as_uint(x);
    return (unsigned short)((u + 0x7fffu + ((u >> 16) & 1u)) >> 16);
}

// W prep: read W[F][K] fp32, write Wt_hi/Wt_lo as [K][F] bf16 (transposed).
__global__ __launch_bounds__(256) void wsplit(const float* __restrict__ W,
                                              unsigned short* __restrict__ thi,
                                              unsigned short* __restrict__ tlo,
                                              int F, int K) {
    int idx = blockIdx.x * 256 + threadIdx.x;
    if (idx >= F * K) return;
    int f = idx / K, k = idx % K;
    float v = W[idx];
    unsigned int u = __float_as_uint(v);
    unsigned int uh = (u + 0x7fffu + ((u >> 16) & 1u)) & 0xffff0000u;
    float lo = v - __uint_as_float(uh);
    thi[k * F + f] = (unsigned short)(uh >> 16);
    tlo[k * F + f] = bf16_rne(lo);
}

// ---------------- MFMA GEMM fused with el/er + bf16 output -----------------
// C[N,K] = A[N,F] @ W[F,K], split-bf16 3-term, K=256 (H=4,D=64).
// 128x128 tile, 4 waves; wave (wr,wc) owns rows [wr,wr+64) x cols [wc,wc+64),
// i.e. exactly head h=(n0+wc)>>6 for 64 rows -> el/er computed in-register
// via lr-group shuffle reduce, no atomics. Output written bf16.

__global__ __launch_bounds__(256) void gemm_mfma(const float* __restrict__ A,
                                                 const unsigned short* __restrict__ Bthi,
                                                 const unsigned short* __restrict__ Btlo,
                                                 unsigned short* __restrict__ featb,
                                                 float* __restrict__ el,
                                                 float* __restrict__ er,
                                                 const float* __restrict__ al,
                                                 const float* __restrict__ ar,
                                                 int N, int F, int K) {
    __shared__ unsigned short As[2][128][40];
    __shared__ unsigned short Bs[2][128][40];
    int tid = threadIdx.x;
    int lane = tid & 63, w = tid >> 6;
    int wr = (w >> 1) * 64, wc = (w & 1) * 64;
    int lr = lane & 15, lq = lane >> 4;
    int m0 = blockIdx.y * 128, n0 = blockIdx.x * 128;
    f32x4 acc[4][4] = {};

    for (int k0 = 0; k0 < F; k0 += 32) {
        __syncthreads();
#pragma unroll
        for (int i = 0; i < 4; ++i) {
            int slot = i * 256 + tid;
            int r = slot >> 3, c = slot & 7;
            int gr = m0 + r;
            float4 v = make_float4(0.f, 0.f, 0.f, 0.f);
            if (gr < N) v = *(const float4*)&A[(size_t)gr * F + k0 + c * 4];
            float vv[4] = {v.x, v.y, v.z, v.w};
            unsigned short h[4], l[4];
#pragma unroll
            for (int j = 0; j < 4; ++j) {
                unsigned int u = __float_as_uint(vv[j]);
                unsigned int uh = (u + 0x7fffu + ((u >> 16) & 1u)) & 0xffff0000u;
                h[j] = (unsigned short)(uh >> 16);
                l[j] = bf16_rne(vv[j] - __uint_as_float(uh));
            }
            *(ushort4*)&As[0][r][c * 4] = make_ushort4(h[0], h[1], h[2], h[3]);
            *(ushort4*)&As[1][r][c * 4] = make_ushort4(l[0], l[1], l[2], l[3]);
        }
#pragma unroll
        for (int i = 0; i < 4; ++i) {
            int slot = i * 256 + tid;
            int s = slot >> 9, r = (slot >> 2) & 127, c = slot & 3;
            const unsigned short* B = s ? Btlo : Bthi;
            uint4 bv = *(const uint4*)&B[(size_t)(n0 + r) * F + k0 + c * 8];
            *(uint4*)&Bs[s][r][c * 8] = bv;
        }
        __syncthreads();

        v8s af[2][4], bf[2][4];
#pragma unroll
        for (int mt = 0; mt < 4; ++mt) {
            af[0][mt] = *(const v8s*)&As[0][wr + mt * 16 + lr][lq * 8];
            af[1][mt] = *(const v8s*)&As[1][wr + mt * 16 + lr][lq * 8];
        }
#pragma unroll
        for (int nt = 0; nt < 4; ++nt) {
            bf[0][nt] = *(const v8s*)&Bs[0][wc + nt * 16 + lr][lq * 8];
            bf[1][nt] = *(const v8s*)&Bs[1][wc + nt * 16 + lr][lq * 8];
        }
#pragma unroll
        for (int mt = 0; mt < 4; ++mt)
#pragma unroll
            for (int nt = 0; nt < 4; ++nt) {
                acc[mt][nt] = __builtin_amdgcn_mfma_f32_16x16x32_bf16(af[0][mt], bf[0][nt], acc[mt][nt], 0, 0, 0);
                acc[mt][nt] = __builtin_amdgcn_mfma_f32_16x16x32_bf16(af[0][mt], bf[1][nt], acc[mt][nt], 0, 0, 0);
                acc[mt][nt] = __builtin_amdgcn_mfma_f32_16x16x32_bf16(af[1][mt], bf[0][nt], acc[mt][nt], 0, 0, 0);
            }
    }

    // ---- fused epilogue ----
    int h = (n0 + wc) >> 6;  // head (D=64)
    float alw[4], arw[4];
#pragma unroll
    for (int nt = 0; nt < 4; ++nt) {
        int d = nt * 16 + lr;
        alw[nt] = al[h * 64 + d];
        arw[nt] = ar[h * 64 + d];
    }
#pragma unroll
    for (int mt = 0; mt < 4; ++mt) {
#pragma unroll
        for (int r = 0; r < 4; ++r) {
            float se = 0.f, sr = 0.f;
#pragma unroll
            for (int nt = 0; nt < 4; ++nt) {
                float v = acc[mt][nt][r];
                se += v * alw[nt];
                sr += v * arw[nt];
            }
#pragma unroll
            for (int o = 8; o >= 1; o >>= 1) {
                se += __shfl_xor(se, o);
                sr += __shfl_xor(sr, o);
            }
            int row = m0 + wr + mt * 16 + lq * 4 + r;
            if (lr == 0 && row < N) {
                el[(size_t)row * 4 + h] = se;
                er[(size_t)row * 4 + h] = sr;
            }
        }
    }
#pragma unroll
    for (int mt = 0; mt < 4; ++mt) {
#pragma unroll
        for (int nt = 0; nt < 4; ++nt) {
            int col = n0 + wc + nt * 16 + lr;
#pragma unroll
            for (int r = 0; r < 4; ++r) {
                int row = m0 + wr + mt * 16 + lq * 4 + r;
                if (row < N) featb[(size_t)row * K + col] = bf16_rne(acc[mt][nt][r]);
            }
        }
    }
}

// ---------------- fp32 GEMM (layer 2 only, K=16) ----------------

__global__ __launch_bounds__(256) void gemm_kernel(const float* __restrict__ A,
                                                   const float* __restrict__ W,
                                                   float* __restrict__ C,
                                                   int N, int F, int K) {
    __shared__ __align__(16) float As2[16][68];
    __shared__ __align__(16) float Ws2[16][64];
    int tid = threadIdx.x;
    int tx = tid & 15, ty = tid >> 4;
    int r0 = blockIdx.y * 64, c0 = blockIdx.x * 64;
    int arow = tid >> 2, akq = tid & 3;
    int wk = tid >> 4, wcq = tid & 15;
    float acc[4][4] = {};

    for (int k0 = 0; k0 < F; k0 += 16) {
        float4 av = make_float4(0.f, 0.f, 0.f, 0.f);
        int gr = r0 + arow;
        if (gr < N) av = *(const float4*)&A[(size_t)gr * F + k0 + akq * 4];
        float4 wv = make_float4(0.f, 0.f, 0.f, 0.f);
        int gc = c0 + wcq * 4;
        if (gc < K) wv = *(const float4*)&W[(size_t)(k0 + wk) * K + gc];
        __syncthreads();
        As2[akq * 4 + 0][arow] = av.x;
        As2[akq * 4 + 1][arow] = av.y;
        As2[akq * 4 + 2][arow] = av.z;
        As2[akq * 4 + 3][arow] = av.w;
        *(float4*)&Ws2[wk][wcq * 4] = wv;
        __syncthreads();
#pragma unroll
        for (int k = 0; k < 16; ++k) {
            float4 a = *(const float4*)&As2[k][ty * 4];
            float4 wv2 = *(const float4*)&Ws2[k][tx * 4];
            acc[0][0] += a.x * wv2.x; acc[0][1] += a.x * wv2.y; acc[0][2] += a.x * wv2.z; acc[0][3] += a.x * wv2.w;
            acc[1][0] += a.y * wv2.x; acc[1][1] += a.y * wv2.y; acc[1][2] += a.y * wv2.z; acc[1][3] += a.y * wv2.w;
            acc[2][0] += a.z * wv2.x; acc[2][1] += a.z * wv2.y; acc[2][2] += a.z * wv2.z; acc[2][3] += a.z * wv2.w;
            acc[3][0] += a.w * wv2.x; acc[3][1] += a.w * wv2.y; acc[3][2] += a.w * wv2.z; acc[3][3] += a.w * wv2.w;
        }
    }
#pragma unroll
    for (int i = 0; i < 4; ++i) {
        int gr = r0 + ty * 4 + i;
        if (gr < N && (c0 + tx * 4) < K) {
            float4 o4 = make_float4(acc[i][0], acc[i][1], acc[i][2], acc[i][3]);
            *(float4*)&C[(size_t)gr * K + c0 + tx * 4] = o4;
        }
    }
}

// ---------------- el/er + bf16 cast (layer 2 only) ----------------

template <int H, int D>
__global__ __launch_bounds__(256) void elr_kernel(const float* __restrict__ feat,
                                                  const float* __restrict__ al,
                                                  const float* __restrict__ ar,
                                                  float* __restrict__ el,
                                                  float* __restrict__ er,
                                                  unsigned short* __restrict__ featb, int N) {
    constexpr int HD = H * D;
    constexpr int G = 256 / HD;
    int tid = threadIdx.x;
    int g = tid / HD;
    int rem = tid % HD;
    int h = rem / D;
    int d = rem % D;
    int n = blockIdx.x * G + g;
    float vl = 0.f, vr = 0.f;
    if (n < N) {
        float f = feat[(size_t)n * HD + rem];
        featb[(size_t)n * HD + rem] = bf16_rne(f);
        vl = f * al[rem];
        vr = f * ar[rem];
    }
#pragma unroll
    for (int o = D / 2; o >= 1; o >>= 1) {
        vl += __shfl_xor(vl, o);
        vr += __shfl_xor(vr, o);
    }
    if (n < N && d == 0) {
        el[n * H + h] = vl;
        er[n * H + h] = vr;
    }
}

// ---------------- agg for H=4, D=64: wave-per-node ----------------
// Fast path (deg<=64): gather csr+el once, e in registers, max+exp+sum in
// one sweep. Slow path (deg>64): looped two-pass via LDS. Phase 3: per edge
// the wave reads the full 512B bf16 row coalesced; alpha via LDS broadcast.

template <int CAP, int U>
__global__ __launch_bounds__(256) void agg4_kernel(const unsigned short* __restrict__ featb,
                                                   const float* __restrict__ el,
                                                   const float* __restrict__ er,
                                                   const float* __restrict__ bias,
                                                   const int* __restrict__ off,
                                                   const int* __restrict__ csr,
                                                   float* __restrict__ out, int N) {
    __shared__ float s_alpha[4][4][CAP];  // [wave][head][edge]
    __shared__ int s_src[4][CAP];
    int w = threadIdx.x >> 6;
    int lane = threadIdx.x & 63;
    int n = blockIdx.x * 4 + w;
    if (n >= N) return;
    int begin = off[n];
    int deg = off[n + 1] - begin;
    float4 ern = *(const float4*)&er[(size_t)n * 4];

    float m0 = -INFINITY, m1 = -INFINITY, m2 = -INFINITY, m3 = -INFINITY;
    float s0 = 0.f, s1 = 0.f, s2 = 0.f, s3 = 0.f;

    if (deg <= 64) {
        // ---- fast path: single sweep, e in registers ----
        bool act = lane < deg;
        int s = 0;
        float e0 = -INFINITY, e1 = -INFINITY, e2 = -INFINITY, e3 = -INFINITY;
        if (act) {
            s = csr[begin + lane];
            float4 e = *(const float4*)&el[(size_t)s * 4];
            e0 = e.x + ern.x; e1 = e.y + ern.y; e2 = e.z + ern.z; e3 = e.w + ern.w;
            e0 = e0 > 0.f ? e0 : NEG_SLOPE * e0;
            e1 = e1 > 0.f ? e1 : NEG_SLOPE * e1;
            e2 = e2 > 0.f ? e2 : NEG_SLOPE * e2;
            e3 = e3 > 0.f ? e3 : NEG_SLOPE * e3;
        }
        m0 = e0; m1 = e1; m2 = e2; m3 = e3;
#pragma unroll
        for (int o = 32; o >= 1; o >>= 1) {
            m0 = fmaxf(m0, __shfl_xor(m0, o));
            m1 = fmaxf(m1, __shfl_xor(m1, o));
            m2 = fmaxf(m2, __shfl_xor(m2, o));
            m3 = fmaxf(m3, __shfl_xor(m3, o));
        }
        if (act) {
            s0 = __expf(e0 - m0); s1 = __expf(e1 - m1);
            s2 = __expf(e2 - m2); s3 = __expf(e3 - m3);
            s_src[w][lane] = s;
            s_alpha[w][0][lane] = s0;
            s_alpha[w][1][lane] = s1;
            s_alpha[w][2][lane] = s2;
            s_alpha[w][3][lane] = s3;
        }
#pragma unroll
        for (int o = 32; o >= 1; o >>= 1) {
            s0 += __shfl_xor(s0, o); s1 += __shfl_xor(s1, o);
            s2 += __shfl_xor(s2, o); s3 += __shfl_xor(s3, o);
        }
    } else {
        // ---- slow path: looped two-pass ----
        for (int i = lane; i < deg; i += 64) {
            int s = csr[begin + i];
            float4 e = *(const float4*)&el[(size_t)s * 4];
            float e0 = e.x + ern.x, e1 = e.y + ern.y, e2 = e.z + ern.z, e3 = e.w + ern.w;
            e0 = e0 > 0.f ? e0 : NEG_SLOPE * e0;
            e1 = e1 > 0.f ? e1 : NEG_SLOPE * e1;
            e2 = e2 > 0.f ? e2 : NEG_SLOPE * e2;
            e3 = e3 > 0.f ? e3 : NEG_SLOPE * e3;
            if (i < CAP) {
                s_src[w][i] = s;
                s_alpha[w][0][i] = e0; s_alpha[w][1][i] = e1;
                s_alpha[w][2][i] = e2; s_alpha[w][3][i] = e3;
            }
            m0 = fmaxf(m0, e0); m1 = fmaxf(m1, e1);
            m2 = fmaxf(m2, e2); m3 = fmaxf(m3, e3);
        }
#pragma unroll
        for (int o = 32; o >= 1; o >>= 1) {
            m0 = fmaxf(m0, __shfl_xor(m0, o));
            m1 = fmaxf(m1, __shfl_xor(m1, o));
            m2 = fmaxf(m2, __shfl_xor(m2, o));
            m3 = fmaxf(m3, __shfl_xor(m3, o));
        }
        for (int i = lane; i < deg; i += 64) {
            float e0, e1, e2, e3;
            if (i < CAP) {
                e0 = s_alpha[w][0][i]; e1 = s_alpha[w][1][i];
                e2 = s_alpha[w][2][i]; e3 = s_alpha[w][3][i];
            } else {
                int s = csr[begin + i];
                float4 e = *(const float4*)&el[(size_t)s * 4];
                e0 = e.x + ern.x; e1 = e.y + ern.y; e2 = e.z + ern.z; e3 = e.w + ern.w;
                e0 = e0 > 0.f ? e0 : NEG_SLOPE * e0;
                e1 = e1 > 0.f ? e1 : NEG_SLOPE * e1;
                e2 = e2 > 0.f ? e2 : NEG_SLOPE * e2;
                e3 = e3 > 0.f ? e3 : NEG_SLOPE * e3;
            }
            e0 = __expf(e0 - m0); e1 = __expf(e1 - m1);
            e2 = __expf(e2 - m2); e3 = __expf(e3 - m3);
            if (i < CAP) {
                s_alpha[w][0][i] = e0; s_alpha[w][1][i] = e1;
                s_alpha[w][2][i] = e2; s_alpha[w][3][i] = e3;
            }
            s0 += e0; s1 += e1; s2 += e2; s3 += e3;
        }
#pragma unroll
        for (int o = 32; o >= 1; o >>= 1) {
            s0 += __shfl_xor(s0, o); s1 += __shfl_xor(s1, o);
            s2 += __shfl_xor(s2, o); s3 += __shfl_xor(s3, o);
        }
    }

    float inv0 = deg > 0 ? 1.f / s0 : 0.f;
    float inv1 = deg > 0 ? 1.f / s1 : 0.f;
    float inv2 = deg > 0 ? 1.f / s2 : 0.f;
    float inv3 = deg > 0 ? 1.f / s3 : 0.f;

    // Phase 3
    int hsel = lane >> 5;  // 0: heads {0,2}; 1: heads {1,3}
    int dcap = deg < CAP ? deg : CAP;
    const unsigned int* frow = (const unsigned int*)featb;
    float a0 = 0.f, a1 = 0.f, a2 = 0.f, a3 = 0.f;
    int j = 0;
    for (; j + U <= dcap; j += U) {
        int s[U];
        unsigned int f0[U], f1[U];
        float aA[U], aB[U];
#pragma unroll
        for (int u = 0; u < U; ++u) s[u] = s_src[w][j + u];
#pragma unroll
        for (int u = 0; u < U; ++u) {
            const unsigned int* rp = frow + (size_t)s[u] * 128;
            f0[u] = rp[lane];
            f1[u] = rp[64 + lane];
        }
#pragma unroll
        for (int u = 0; u < U; ++u) {
            aA[u] = s_alpha[w][hsel][j + u];
            aB[u] = s_alpha[w][2 + hsel][j + u];
        }
#pragma unroll
        for (int u = 0; u < U; ++u) {
            a0 += aA[u] * __uint_as_float(f0[u] << 16);
            a1 += aA[u] * __uint_as_float(f0[u] & 0xffff0000u);
            a2 += aB[u] * __uint_as_float(f1[u] << 16);
            a3 += aB[u] * __uint_as_float(f1[u] & 0xffff0000u);
        }
    }
    for (; j < dcap; ++j) {
        int s = s_src[w][j];
        const unsigned int* rp = frow + (size_t)s * 128;
        unsigned int f0v = rp[lane], f1v = rp[64 + lane];
        float aA = s_alpha[w][hsel][j], aB = s_alpha[w][2 + hsel][j];
        a0 += aA * __uint_as_float(f0v << 16);
        a1 += aA * __uint_as_float(f0v & 0xffff0000u);
        a2 += aB * __uint_as_float(f1v << 16);
        a3 += aB * __uint_as_float(f1v & 0xffff0000u);
    }
    // spill path deg > CAP (bf16 gather, recompute alpha)
    for (int i = CAP; i < deg; ++i) {
        int s = csr[begin + i];
        float4 e = *(const float4*)&el[(size_t)s * 4];
        float e0 = e.x + ern.x, e1 = e.y + ern.y, e2 = e.z + ern.z, e3 = e.w + ern.w;
        e0 = e0 > 0.f ? e0 : NEG_SLOPE * e0;
        e1 = e1 > 0.f ? e1 : NEG_SLOPE * e1;
        e2 = e2 > 0.f ? e2 : NEG_SLOPE * e2;
        e3 = e3 > 0.f ? e3 : NEG_SLOPE * e3;
        float x0 = __expf(e0 - m0), x1 = __expf(e1 - m1);
        float x2 = __expf(e2 - m2), x3 = __expf(e3 - m3);
        float aA = hsel ? x1 : x0, aB = hsel ? x3 : x2;
        const unsigned int* rp = frow + (size_t)s * 128;
        unsigned int f0v = rp[lane], f1v = rp[64 + lane];
        a0 += aA * __uint_as_float(f0v << 16);
        a1 += aA * __uint_as_float(f0v & 0xffff0000u);
        a2 += aB * __uint_as_float(f1v << 16);
        a3 += aB * __uint_as_float(f1v & 0xffff0000u);
    }
    float invA = hsel ? inv1 : inv0;
    float invB = hsel ? inv3 : inv2;
    float2 o0 = make_float2(a0 * invA + bias[2 * lane], a1 * invA + bias[2 * lane + 1]);
    float2 o1 = make_float2(a2 * invB + bias[128 + 2 * lane], a3 * invB + bias[128 + 2 * lane + 1]);
    *(float2*)&out[(size_t)n * 256 + 2 * lane] = o0;
    *(float2*)&out[(size_t)n * 256 + 128 + 2 * lane] = o1;
}

// ---------------- agg for H=1, D=16 (layer 2) ----------------

template <int H, int D, int CAP, int U>
__global__ __launch_bounds__(H * 64) void agg_kernel(const unsigned short* __restrict__ featb,
                                                     const float* __restrict__ feat,
                                                     const float* __restrict__ el,
                                                     const float* __restrict__ er,
                                                     const float* __restrict__ bias,
                                                     const int* __restrict__ off,
                                                     const int* __restrict__ csr,
                                                     float* __restrict__ out, int N) {
    constexpr int HD = H * D;
    constexpr int L = D / 2;
    constexpr int ES = 64 / L;
    __shared__ float s_alpha[H][CAP];
    __shared__ int s_src[CAP];
    int n = blockIdx.x;
    int h = threadIdx.x >> 6;
    int lane = threadIdx.x & 63;
    int begin = off[n];
    int deg = off[n + 1] - begin;
    float er_nh = er[n * H + h];

    float m = -INFINITY;
    for (int i = lane; i < deg; i += 64) {
        int s = csr[begin + i];
        if (h == 0 && i < CAP) s_src[i] = s;
        float e = el[s * H + h] + er_nh;
        e = e > 0.f ? e : NEG_SLOPE * e;
        if (i < CAP) s_alpha[h][i] = e;
        m = fmaxf(m, e);
    }
#pragma unroll
    for (int o = 32; o >= 1; o >>= 1) m = fmaxf(m, __shfl_xor(m, o));

    float ss = 0.f;
    for (int i = lane; i < deg; i += 64) {
        float e;
        if (i < CAP) e = s_alpha[h][i];
        else {
            int s = csr[begin + i];
            e = el[s * H + h] + er_nh;
            e = e > 0.f ? e : NEG_SLOPE * e;
        }
        float x = __expf(e - m);
        ss += x;
        if (i < CAP) s_alpha[h][i] = x;
    }
#pragma unroll
    for (int o = 32; o >= 1; o >>= 1) ss += __shfl_xor(ss, o);
    float inv = (deg > 0) ? 1.f / ss : 0.f;

    __syncthreads();

    int slot = lane / L;
    int p = lane % L;
    int dcap = deg < CAP ? deg : CAP;
    const unsigned int* frow = (const unsigned int*)featb;
    size_t colOff = (size_t)(h * D) / 2 + p;
    float accx = 0.f, accy = 0.f;
    int j = slot;
    for (; j + (U - 1) * ES < dcap; j += U * ES) {
        float a[U];
        unsigned int f[U];
        int s[U];
#pragma unroll
        for (int u = 0; u < U; ++u) {
            int idx = j + u * ES;
            s[u] = s_src[idx];
            a[u] = s_alpha[h][idx];
        }
#pragma unroll
        for (int u = 0; u < U; ++u)
            f[u] = frow[(size_t)s[u] * (HD / 2) + colOff];
#pragma unroll
        for (int u = 0; u < U; ++u) {
            accx += a[u] * __uint_as_float(f[u] << 16);
            accy += a[u] * __uint_as_float(f[u] & 0xffff0000u);
        }
    }
    for (; j < dcap; j += ES) {
        float a = s_alpha[h][j];
        unsigned int f = frow[(size_t)s_src[j] * (HD / 2) + colOff];
        accx += a * __uint_as_float(f << 16);
        accy += a * __uint_as_float(f & 0xffff0000u);
    }
    for (int i = CAP + slot; i < deg; i += ES) {
        int s = csr[begin + i];
        float e = el[s * H + h] + er_nh;
        e = e > 0.f ? e : NEG_SLOPE * e;
        float wex = __expf(e - m);
        accx += wex * feat[(size_t)s * HD + h * D + 2 * p];
        accy += wex * feat[(size_t)s * HD + h * D + 2 * p + 1];
    }
#pragma unroll
    for (int o = L; o < 64; o <<= 1) {
        accx += __shfl_xor(accx, o);
        accy += __shfl_xor(accy, o);
    }
    if (lane < L) {
        float2 o2 = make_float2(accx * inv + bias[h * D + 2 * p],
                                accy * inv + bias[h * D + 2 * p + 1]);
        *(float2*)&out[(size_t)n * HD + h * D + 2 * p] = o2;
    }
}

// ---------------- launch ----------------

extern "C" void kernel_launch(void* const* d_in, const int* in_sizes, int n_in,
                              void* d_out, int out_size, void* d_ws, size_t ws_size,
                              hipStream_t stream) {
    const float* inputs = (const float*)d_in[0];
    const float* W0 = (const float*)d_in[1];
    const float* al0 = (const float*)d_in[2];
    const float* ar0 = (const float*)d_in[3];
    const float* b0 = (const float*)d_in[4];
    const float* W1 = (const float*)d_in[5];
    const float* al1 = (const float*)d_in[6];
    const float* ar1 = (const float*)d_in[7];
    const float* b1 = (const float*)d_in[8];
    const float* W2 = (const float*)d_in[9];
    const float* al2 = (const float*)d_in[10];
    const float* ar2 = (const float*)d_in[11];
    const float* b2 = (const float*)d_in[12];
    const int* src = (const int*)d_in[13];
    const int* dst = (const int*)d_in[14];

    const int IN_DIM = 128;
    const int N = in_sizes[0] / IN_DIM;  // 50000
    const int E = in_sizes[13];          // 800000
    float* out = (float*)d_out;

    char* base = (char*)d_ws;
    size_t o = 0;
    auto carve = [&](size_t bytes) -> void* {
        void* p = base + o;
        o += (bytes + 255) & ~(size_t)255;
        return p;
    };
    int* off = (int*)carve((size_t)(N + 1) * sizeof(int));
    int* cursor = (int*)carve((size_t)N * sizeof(int));
    int* chunkSum = (int*)carve(64 * sizeof(int));
    int* chunkOff = (int*)carve(64 * sizeof(int));
    int* csr = (int*)carve((size_t)E * sizeof(int));
    float* el = (float*)carve((size_t)N * 4 * sizeof(float));
    float* er = (float*)carve((size_t)N * 4 * sizeof(float));
    float* feat = (float*)carve((size_t)N * 16 * sizeof(float));  // layer-2 fp32 feat only
    float* hbuf = (float*)carve((size_t)N * 256 * sizeof(float));
    unsigned short* featb = (unsigned short*)carve((size_t)N * 256 * sizeof(unsigned short));
    unsigned short* wt0hi = (unsigned short*)carve((size_t)128 * 256 * sizeof(unsigned short));
    unsigned short* wt0lo = (unsigned short*)carve((size_t)128 * 256 * sizeof(unsigned short));
    unsigned short* wt1hi = (unsigned short*)carve((size_t)256 * 256 * sizeof(unsigned short));
    unsigned short* wt1lo = (unsigned short*)carve((size_t)256 * 256 * sizeof(unsigned short));

    // ---- CSR build ----
    hipMemsetAsync(off, 0, (size_t)(N + 1) * sizeof(int), stream);
    int egrid = (E + 255) / 256;
    count_deg<<<egrid, 256, 0, stream>>>(dst, off, E);
    int nchunks = (N + 2047) / 2048;
    scan_chunk<<<nchunks, 256, 0, stream>>>(off, chunkSum, N);
    scan_tail<<<1, 64, 0, stream>>>(chunkSum, chunkOff, nchunks, off, N, E);
    add_chunk_off<<<(N + 255) / 256, 256, 0, stream>>>(off, cursor, chunkOff, N);
    scatter_edges<<<egrid, 256, 0, stream>>>(src, dst, cursor, csr, E);

    // ---- W prep (split + transpose) ----
    wsplit<<<(128 * 256 + 255) / 256, 256, 0, stream>>>(W0, wt0hi, wt0lo, 128, 256);
    wsplit<<<(256 * 256 + 255) / 256, 256, 0, stream>>>(W1, wt1hi, wt1lo, 256, 256);

    // ---- Layer 0: 128 -> 4x64 (MFMA, fused elr) ----
    {
        dim3 grid(256 / 128, (N + 127) / 128);
        gemm_mfma<<<grid, 256, 0, stream>>>(inputs, wt0hi, wt0lo, featb, el, er, al0, ar0, N, 128, 256);
        agg4_kernel<64, 8><<<(N + 3) / 4, 256, 0, stream>>>(featb, el, er, b0, off, csr, hbuf, N);
    }
    // ---- Layer 1: 256 -> 4x64 (MFMA, fused elr) ----
    {
        dim3 grid(256 / 128, (N + 127) / 128);
        gemm_mfma<<<grid, 256, 0, stream>>>(hbuf, wt1hi, wt1lo, featb, el, er, al1, ar1, N, 256, 256);
        agg4_kernel<64, 8><<<(N + 3) / 4, 256, 0, stream>>>(featb, el, er, b1, off, csr, hbuf, N);
    }
    // ---- Layer 2: 256 -> 1x16 (fp32 vector GEMM, tiny) ----
    {
        dim3 grid((16 + 63) / 64, (N + 63) / 64);
        gemm_kernel<<<grid, 256, 0, stream>>>(hbuf, W2, feat, N, 256, 16);
        elr_kernel<1, 16><<<(N + 15) / 16, 256, 0, stream>>>(feat, al2, ar2, el, er, featb, N);
        agg_kernel<1, 16, 512, 2><<<N, 64, 0, stream>>>(featb, feat, el, er, b2, off, csr, out, N);
    }
}